// Round 1
// baseline (301.272 us; speedup 1.0000x reference)
//
#include <hip/hip_runtime.h>
#include <math.h>

#define B_    2
#define HC_   96
#define WC_   96
#define HF_   384
#define WF_   384
#define CINC_ 256
#define CH_   64
#define COUT_ 19

// ---------------- K0: weight transposes (tiny) ----------------
// w_ec (64,256,3,3) -> w_ec_t (256,9,64)   [c][tap][oc]
// w_v  (19,320)     -> w_vc_t (256,20) [c][ov pad20], w_vq_t (64,20) [c][ov pad20]
// w_q  (64,3)       -> w_q_t  (3,64)   [ci][oc]
__global__ __launch_bounds__(256) void k_prep(
    const float* __restrict__ w_ec, const float* __restrict__ w_v,
    const float* __restrict__ w_q,
    float* __restrict__ w_ec_t, float* __restrict__ w_vc_t,
    float* __restrict__ w_vq_t, float* __restrict__ w_q_t)
{
    int i = blockIdx.x * 256 + threadIdx.x;
    if (i < CH_ * CINC_ * 9) {
        int oc = i / (CINC_ * 9);
        int r  = i - oc * (CINC_ * 9);
        int c  = r / 9;
        int t  = r - c * 9;
        w_ec_t[(c * 9 + t) * CH_ + oc] = w_ec[i];
    }
    if (i < COUT_ * 320) {
        int ov = i / 320;
        int c  = i - ov * 320;
        float val = w_v[i];
        if (c < CINC_) w_vc_t[c * 20 + ov] = val;
        else           w_vq_t[(c - CINC_) * 20 + ov] = val;
    }
    if (i < CH_ * 3) {
        int oc = i / 3, ci = i - oc * 3;
        w_q_t[ci * CH_ + oc] = w_q[i];
    }
}

// ---------------- K1: coarse stage ----------------
// Computes eh_part[z][b][pix] = sum over this block's 32 ec-channels of
// w_eh[oc]*relu(conv3x3(coarse)+b_ec), and cv[b][pix][ov] = w_v[:, :256]·coarse.
// Tile 8x8 pixels, 4 waves x 8 oc, grid.z = 2 oc-split halves.
__global__ __launch_bounds__(256) void k_coarse(
    const float* __restrict__ x,        // (B,256,96,96)
    const float* __restrict__ w_ec_t,   // (256,9,64)
    const float* __restrict__ b_ec,     // (64)
    const float* __restrict__ w_eh,     // (65)
    const float* __restrict__ w_vc_t,   // (256,20)
    float* __restrict__ eh_part,        // (2,B,96*96)
    float* __restrict__ cv)             // (B,96*96,20)
{
    __shared__ float sIn[32][10][10];
    __shared__ float sEh[4][64];

    const int tid = threadIdx.x;
    const int wv  = __builtin_amdgcn_readfirstlane(tid >> 6);
    const int pix = tid & 63;
    const int py = pix >> 3, px = pix & 7;
    const int tile = blockIdx.x;            // 0..143
    const int b = blockIdx.y;
    const int z = blockIdx.z;               // oc-split half
    const int ty0 = (tile / 12) * 8;
    const int tx0 = (tile % 12) * 8;

    const int oc0 = z * 32 + wv * 8;
    const int g   = z * 4 + wv;             // 0..7 global wave slot
    const int cv_s = (COUT_ * g) >> 3;
    const int cv_e = (COUT_ * (g + 1)) >> 3;   // <= cv_s+3

    float acc[8];
    #pragma unroll
    for (int j = 0; j < 8; ++j) acc[j] = 0.f;
    float accv[3] = {0.f, 0.f, 0.f};

    const float* xb = x + (size_t)b * CINC_ * (HC_ * WC_);

    for (int c0 = 0; c0 < CINC_; c0 += 32) {
        __syncthreads();
        for (int i = tid; i < 3200; i += 256) {
            int cc = i / 100;
            int pp = i - cc * 100;
            int iy = pp / 10, ix = pp - iy * 10;
            int gy = ty0 + iy - 1, gx = tx0 + ix - 1;
            float v = 0.f;
            if (gy >= 0 && gy < HC_ && gx >= 0 && gx < WC_)
                v = xb[(size_t)(c0 + cc) * (HC_ * WC_) + gy * WC_ + gx];
            sIn[cc][iy][ix] = v;
        }
        __syncthreads();
        for (int cc = 0; cc < 32; ++cc) {
            float nb[9];
            #pragma unroll
            for (int ky = 0; ky < 3; ++ky)
                #pragma unroll
                for (int kx = 0; kx < 3; ++kx)
                    nb[ky * 3 + kx] = sIn[cc][py + ky][px + kx];
            const float* wt = w_ec_t + (size_t)(c0 + cc) * 9 * CH_ + oc0;
            #pragma unroll
            for (int t = 0; t < 9; ++t) {
                float nv = nb[t];
                #pragma unroll
                for (int j = 0; j < 8; ++j)
                    acc[j] = fmaf(wt[t * CH_ + j], nv, acc[j]);
            }
            const float* wvp = w_vc_t + (size_t)(c0 + cc) * 20;
            float ctr = nb[4];
            #pragma unroll
            for (int j = 0; j < 3; ++j)
                if (cv_s + j < cv_e)
                    accv[j] = fmaf(wvp[cv_s + j], ctr, accv[j]);
        }
    }

    float ehp = 0.f;
    #pragma unroll
    for (int j = 0; j < 8; ++j) {
        float e = fmaxf(acc[j] + b_ec[oc0 + j], 0.f);
        ehp = fmaf(w_eh[oc0 + j], e, ehp);
    }
    sEh[wv][pix] = ehp;

    const int gpix = (ty0 + py) * WC_ + (tx0 + px);
    float* cvp = cv + ((size_t)b * (HC_ * WC_) + gpix) * 20;
    #pragma unroll
    for (int j = 0; j < 3; ++j)
        if (cv_s + j < cv_e) cvp[cv_s + j] = accv[j];

    __syncthreads();
    if (wv == 0) {
        float s = sEh[0][pix] + sEh[1][pix] + sEh[2][pix] + sEh[3][pix];
        eh_part[((size_t)z * B_ + b) * (HC_ * WC_) + gpix] = s;
    }
}

// ---------------- K2: fused fine stage ----------------
__device__ __forceinline__ unsigned short f2bf(float f) {
    unsigned int u = __float_as_uint(f);
    u += 0x7fffu + ((u >> 16) & 1u);
    return (unsigned short)(u >> 16);
}
__device__ __forceinline__ float bflo(unsigned int u) { return __uint_as_float(u << 16); }
__device__ __forceinline__ float bfhi(unsigned int u) { return __uint_as_float(u & 0xffff0000u); }

__global__ __launch_bounds__(256) void k_fine(
    const float* __restrict__ raw,     // (B,3,384,384)
    const float* __restrict__ w_ef,    // 27
    const float* __restrict__ b_ef,    // 1
    const float* __restrict__ w_eh,    // 65
    const float* __restrict__ w_q_t,   // (3,64)
    const float* __restrict__ b_q,     // 64
    const float* __restrict__ w_vq_t,  // (64,20)
    const float* __restrict__ b_v,     // 19
    const float* __restrict__ eh_part, // (2,B,9216)
    const float* __restrict__ cv,      // (B,9216,20)
    float* __restrict__ out_y,         // (B,19,384,384)
    float* __restrict__ out_ne)        // (B,384,384)
{
    __shared__ unsigned short sQ[18][18][68];   // bf16, pad 64->68 (stride 136B: 2-way banks, free)
    __shared__ unsigned short sV[18][18][20];   // bf16 (19 used)
    __shared__ float sNE[18][18];

    const int tid = threadIdx.x;
    const int b   = blockIdx.z;
    const int ty0 = blockIdx.y * 16;
    const int tx0 = blockIdx.x * 16;
    const float* rb = raw + (size_t)b * 3 * (HF_ * WF_);

    // Phase 1: per halo pixel (18x18): ef, non_edge, q, v
    for (int p = tid; p < 324; p += 256) {
        const int iy = p / 18, ix = p - iy * 18;
        const int gh = ty0 + iy - 1, gw = tx0 + ix - 1;
        unsigned int* qrow = (unsigned int*)sQ[iy][ix];
        unsigned int* vrow = (unsigned int*)sV[iy][ix];
        if (gh < 0 || gh >= HF_ || gw < 0 || gw >= WF_) {
            // zero-padded k and v => score 0, contribution 0
            #pragma unroll
            for (int c2 = 0; c2 < 32; ++c2) qrow[c2] = 0u;
            #pragma unroll
            for (int o2 = 0; o2 < 9; ++o2) vrow[o2] = 0u;
            sV[iy][ix][18] = 0;
            sNE[iy][ix] = 0.f;
            continue;
        }
        float r[3][9];
        #pragma unroll
        for (int dy = 0; dy < 3; ++dy) {
            #pragma unroll
            for (int dx = 0; dx < 3; ++dx) {
                int hh = gh + dy - 1, ww = gw + dx - 1;
                bool ok = (hh >= 0) & (hh < HF_) & (ww >= 0) & (ww < WF_);
                size_t off = (size_t)hh * WF_ + ww;
                #pragma unroll
                for (int ci = 0; ci < 3; ++ci)
                    r[ci][dy * 3 + dx] = ok ? rb[(size_t)ci * (HF_ * WF_) + off] : 0.f;
            }
        }
        float ef = b_ef[0];
        #pragma unroll
        for (int ci = 0; ci < 3; ++ci)
            #pragma unroll
            for (int t = 0; t < 9; ++t)
                ef = fmaf(w_ef[ci * 9 + t], r[ci][t], ef);
        ef = fmaxf(ef, 0.f);

        const int cpix = (gh >> 2) * WC_ + (gw >> 2);
        float logit = eh_part[(size_t)b * (HC_ * WC_) + cpix]
                    + eh_part[(size_t)(B_ + b) * (HC_ * WC_) + cpix]
                    + w_eh[64] * ef;
        float ne = 1.f / (1.f + __expf(-logit));
        sNE[iy][ix] = ne;

        float q[64];
        const float r0 = r[0][4], r1 = r[1][4], r2 = r[2][4];
        #pragma unroll
        for (int oc = 0; oc < 64; ++oc) {
            float t = fmaf(w_q_t[oc], r0, b_q[oc]);
            t = fmaf(w_q_t[64 + oc], r1, t);
            q[oc] = fmaf(w_q_t[128 + oc], r2, t);
        }
        #pragma unroll
        for (int c2 = 0; c2 < 32; ++c2)
            qrow[c2] = (unsigned int)f2bf(q[2 * c2]) | ((unsigned int)f2bf(q[2 * c2 + 1]) << 16);

        float v[COUT_];
        const float* cvp = cv + ((size_t)b * (HC_ * WC_) + cpix) * 20;
        #pragma unroll
        for (int ov = 0; ov < COUT_; ++ov) v[ov] = cvp[ov] + b_v[ov];
        #pragma unroll
        for (int c = 0; c < 64; ++c) {
            float qc = q[c];
            #pragma unroll
            for (int ov = 0; ov < COUT_; ++ov)
                v[ov] = fmaf(w_vq_t[c * 20 + ov], qc, v[ov]);
        }
        #pragma unroll
        for (int o2 = 0; o2 < 9; ++o2)
            vrow[o2] = (unsigned int)f2bf(v[2 * o2]) | ((unsigned int)f2bf(v[2 * o2 + 1]) << 16);
        sV[iy][ix][18] = f2bf(v[18]);
    }
    __syncthreads();

    // Phase 2: local attention for own pixel
    const int py = tid >> 4, px = tid & 15;
    const int iy = py + 1, ix = px + 1;

    float qs[64];
    {
        const unsigned int* qp = (const unsigned int*)sQ[iy][ix];
        #pragma unroll
        for (int c2 = 0; c2 < 32; ++c2) {
            unsigned int u = qp[c2];
            qs[2 * c2]     = bflo(u);
            qs[2 * c2 + 1] = bfhi(u);
        }
    }
    float sc[9];
    #pragma unroll
    for (int k = 0; k < 9; ++k) {
        const int ny = iy + k / 3 - 1, nx = ix + k % 3 - 1;
        const unsigned int* qp = (const unsigned int*)sQ[ny][nx];
        float d = 0.f;
        #pragma unroll
        for (int c2 = 0; c2 < 32; ++c2) {
            unsigned int u = qp[c2];
            d = fmaf(qs[2 * c2], bflo(u), d);
            d = fmaf(qs[2 * c2 + 1], bfhi(u), d);
        }
        sc[k] = sNE[ny][nx] * d;   // k = non_edge * q  =>  q·k_nbr = ne_nbr*(q·q_nbr)
    }
    float m = sc[0];
    #pragma unroll
    for (int k = 1; k < 9; ++k) m = fmaxf(m, sc[k]);
    float e[9];
    float ssum = 0.f;
    #pragma unroll
    for (int k = 0; k < 9; ++k) { e[k] = __expf(sc[k] - m); ssum += e[k]; }
    const float inv = 1.f / ssum;

    float y[COUT_];
    #pragma unroll
    for (int ov = 0; ov < COUT_; ++ov) y[ov] = 0.f;
    #pragma unroll
    for (int k = 0; k < 9; ++k) {
        const int ny = iy + k / 3 - 1, nx = ix + k % 3 - 1;
        const float a = e[k] * inv;
        const unsigned int* vp = (const unsigned int*)sV[ny][nx];
        #pragma unroll
        for (int o2 = 0; o2 < 9; ++o2) {
            unsigned int u = vp[o2];
            y[2 * o2]     = fmaf(a, bflo(u), y[2 * o2]);
            y[2 * o2 + 1] = fmaf(a, bfhi(u), y[2 * o2 + 1]);
        }
        y[18] = fmaf(a, bflo((unsigned int)sV[ny][nx][18]), y[18]);
    }

    const int gh = ty0 + py, gw = tx0 + px;
    const size_t ppos = (size_t)gh * WF_ + gw;
    #pragma unroll
    for (int ov = 0; ov < COUT_; ++ov)
        out_y[((size_t)b * COUT_ + ov) * (HF_ * WF_) + ppos] = y[ov];
    out_ne[(size_t)b * (HF_ * WF_) + ppos] = sNE[iy][ix];
}

// ---------------- launch ----------------
extern "C" void kernel_launch(void* const* d_in, const int* in_sizes, int n_in,
                              void* d_out, int out_size, void* d_ws, size_t ws_size,
                              hipStream_t stream)
{
    const float* coarse = (const float*)d_in[0];
    const float* raw    = (const float*)d_in[1];
    const float* w_ef   = (const float*)d_in[2];
    const float* b_ef   = (const float*)d_in[3];
    const float* w_ec   = (const float*)d_in[4];
    const float* b_ec   = (const float*)d_in[5];
    const float* w_eh   = (const float*)d_in[6];
    const float* w_q    = (const float*)d_in[7];
    const float* b_q    = (const float*)d_in[8];
    const float* w_v    = (const float*)d_in[9];
    const float* b_v    = (const float*)d_in[10];
    (void)in_sizes; (void)n_in; (void)out_size; (void)ws_size;

    float* ws      = (float*)d_ws;
    float* w_ec_t  = ws;                  // 147456
    float* w_vc_t  = w_ec_t + 147456;     // 5120
    float* w_vq_t  = w_vc_t + 5120;       // 1280
    float* w_q_t   = w_vq_t + 1280;       // 192
    float* eh_part = w_q_t + 192;         // 2*2*9216 = 36864
    float* cvb     = eh_part + 36864;     // 2*9216*20 = 368640
    // total ~2.24 MB of d_ws

    float* out_y  = (float*)d_out;
    float* out_ne = out_y + (size_t)B_ * COUT_ * HF_ * WF_;

    hipLaunchKernelGGL(k_prep, dim3(576), dim3(256), 0, stream,
                       w_ec, w_v, w_q, w_ec_t, w_vc_t, w_vq_t, w_q_t);
    hipLaunchKernelGGL(k_coarse, dim3(144, B_, 2), dim3(256), 0, stream,
                       coarse, w_ec_t, b_ec, w_eh, w_vc_t, eh_part, cvb);
    hipLaunchKernelGGL(k_fine, dim3(24, 24, B_), dim3(256), 0, stream,
                       raw, w_ef, b_ef, w_eh, w_q_t, b_q, w_vq_t, b_v,
                       eh_part, cvb, out_y, out_ne);
}

// Round 4
// 147.409 us; speedup vs baseline: 2.0438x; 2.0438x over previous
//
#include <hip/hip_runtime.h>
#include <math.h>

#define B_    2
#define HC_   96
#define WC_   96
#define HF_   384
#define WF_   384
#define CINC_ 256
#define CH_   64
#define COUT_ 19

typedef __attribute__((ext_vector_type(8))) short bf16x8;
typedef __attribute__((ext_vector_type(4))) float f32x4;

__device__ __forceinline__ unsigned short f2bf(float f) {
    unsigned int u = __float_as_uint(f);
    u += 0x7fffu + ((u >> 16) & 1u);
    return (unsigned short)(u >> 16);
}
__device__ __forceinline__ float bflo(unsigned int u) { return __uint_as_float(u << 16); }
__device__ __forceinline__ float bfhi(unsigned int u) { return __uint_as_float(u & 0xffff0000u); }

// ---------------- K0: weight prep ----------------
// A_pk  (9,8,4,64,8) bf16 : ec weights in 16x16x32 A-frag layout
//   element = w_ec[oc = m*16+(l&15)][ch = ck*32+(l>>4)*8+e][tap]
// Avc   (8,2,64,8) bf16 : w_v[:, :256] (center-tap cv GEMM), ov>=19 -> 0
// Avq   (2,2,64,8) bf16 : w_v[:, 256:320] (v-from-q GEMM in k_fine)
// w_q_t (3,64) f32
__global__ __launch_bounds__(256) void k_prep(
    const float* __restrict__ w_ec, const float* __restrict__ w_v,
    const float* __restrict__ w_q,
    unsigned short* __restrict__ A_pk, unsigned short* __restrict__ Avc,
    unsigned short* __restrict__ Avq, float* __restrict__ w_q_t)
{
    int i = blockIdx.x * 256 + threadIdx.x;
    if (i < 147456) {
        int e = i & 7, l = (i >> 3) & 63, m = (i >> 9) & 3, ck = (i >> 11) & 7, tap = i >> 14;
        int oc = m * 16 + (l & 15);
        int ch = ck * 32 + (l >> 4) * 8 + e;
        A_pk[i] = f2bf(w_ec[(oc * 256 + ch) * 9 + tap]);
    }
    if (i < 8192) {
        int e = i & 7, l = (i >> 3) & 63, m = (i >> 9) & 1, ck = (i >> 10) & 7;
        int ov = m * 16 + (l & 15);
        int ch = ck * 32 + (l >> 4) * 8 + e;
        Avc[i] = (ov < COUT_) ? f2bf(w_v[ov * 320 + ch]) : (unsigned short)0;
    }
    if (i < 2048) {
        int e = i & 7, l = (i >> 3) & 63, m = (i >> 9) & 1, ck = (i >> 10) & 1;
        int ov = m * 16 + (l & 15);
        int ch = 256 + ck * 32 + (l >> 4) * 8 + e;
        Avq[i] = (ov < COUT_) ? f2bf(w_v[ov * 320 + ch]) : (unsigned short)0;
    }
    if (i < 192) {
        int oc = i / 3, ci = i - oc * 3;
        w_q_t[ci * 64 + oc] = w_q[i];
    }
}

// ---------------- K_xt: coarse (B,256,96,96) f32 -> Xt (B,98,98,256) bf16 ----------------
// Border (row/col 0 and 97) pre-zeroed by hipMemsetAsync; we write interior only.
__global__ __launch_bounds__(256) void k_xt(
    const float* __restrict__ x, unsigned short* __restrict__ Xt)
{
    const int b  = blockIdx.y;
    const int px = blockIdx.x * 256 + threadIdx.x;      // 0..9215
    const int gy = px / 96, gx = px - gy * 96;
    const float* src = x + (size_t)b * CINC_ * 9216;
    unsigned short* dst = Xt + (((size_t)(b * 98 + gy + 1)) * 98 + gx + 1) * 256;
    for (int c0 = 0; c0 < 256; c0 += 8) {
        float f[8];
        #pragma unroll
        for (int t = 0; t < 8; ++t) f[t] = src[(size_t)(c0 + t) * 9216 + px];
        uint4 u;
        u.x = (unsigned int)f2bf(f[0]) | ((unsigned int)f2bf(f[1]) << 16);
        u.y = (unsigned int)f2bf(f[2]) | ((unsigned int)f2bf(f[3]) << 16);
        u.z = (unsigned int)f2bf(f[4]) | ((unsigned int)f2bf(f[5]) << 16);
        u.w = (unsigned int)f2bf(f[6]) | ((unsigned int)f2bf(f[7]) << 16);
        *(uint4*)&dst[c0] = u;
    }
}

// ---------------- K_ec: MFMA conv3x3 (ec) + fused cv GEMM ----------------
// grid (6,6,B). 4 waves; wave w: rows 4w..4w+3 of a 16x16 px tile, 64 oc (4 m-tiles).
// B staged per 32-ch chunk in LDS: [324 px][40 halfs] (80B stride -> 2-way banks, free).
__global__ __launch_bounds__(256, 1) void k_ec(
    const unsigned short* __restrict__ Xt,
    const unsigned short* __restrict__ A_pk,
    const unsigned short* __restrict__ Avc,
    const float* __restrict__ b_ec, const float* __restrict__ w_eh,
    float* __restrict__ eh_out,          // (B,9216)
    float* __restrict__ cvb)             // (B,9216,20)
{
    __shared__ unsigned short sB[324 * 40];

    const int tid  = threadIdx.x;
    const int lane = tid & 63;
    const int wv   = tid >> 6;
    const int j    = lane & 15;
    const int g    = lane >> 4;
    const int b    = blockIdx.z;
    const int ty0  = blockIdx.y * 16;
    const int tx0  = blockIdx.x * 16;

    f32x4 acc[4][4];
    f32x4 accv[2][4];
    #pragma unroll
    for (int m = 0; m < 4; ++m)
        #pragma unroll
        for (int r = 0; r < 4; ++r) acc[m][r] = (f32x4)0.f;
    #pragma unroll
    for (int m = 0; m < 2; ++m)
        #pragma unroll
        for (int r = 0; r < 4; ++r) accv[m][r] = (f32x4)0.f;

    const bf16x8* Af  = (const bf16x8*)A_pk;
    const bf16x8* Avf = (const bf16x8*)Avc;

    int pxbase[4];
    #pragma unroll
    for (int r = 0; r < 4; ++r) pxbase[r] = ((4 * wv + r) * 18 + j) * 40 + g * 8;

    for (int ck = 0; ck < 8; ++ck) {
        __syncthreads();
        for (int i = tid; i < 1296; i += 256) {
            int px = i >> 2, part = i & 3;
            int ty = px / 18, tx = px - ty * 18;
            const unsigned short* src = Xt
                + (((size_t)(b * 98 + ty0 + ty)) * 98 + (tx0 + tx)) * 256
                + ck * 32 + part * 8;
            *(uint4*)&sB[px * 40 + part * 8] = *(const uint4*)src;
        }
        __syncthreads();

        #pragma unroll
        for (int tap = 0; tap < 9; ++tap) {
            const int dy = tap / 3, dx = tap % 3;
            bf16x8 bfr[4];
            #pragma unroll
            for (int r = 0; r < 4; ++r)
                bfr[r] = *(const bf16x8*)&sB[pxbase[r] + (dy * 18 + dx) * 40];
            bf16x8 afr[4];
            #pragma unroll
            for (int m = 0; m < 4; ++m)
                afr[m] = Af[((tap * 8 + ck) * 4 + m) * 64 + lane];
            #pragma unroll
            for (int m = 0; m < 4; ++m)
                #pragma unroll
                for (int r = 0; r < 4; ++r)
                    acc[m][r] = __builtin_amdgcn_mfma_f32_16x16x32_bf16(afr[m], bfr[r], acc[m][r], 0, 0, 0);
            if (tap == 4) {  // center tap: cv GEMM shares the B-frags
                bf16x8 av[2];
                #pragma unroll
                for (int m = 0; m < 2; ++m)
                    av[m] = Avf[(ck * 2 + m) * 64 + lane];
                #pragma unroll
                for (int m = 0; m < 2; ++m)
                    #pragma unroll
                    for (int r = 0; r < 4; ++r)
                        accv[m][r] = __builtin_amdgcn_mfma_f32_16x16x32_bf16(av[m], bfr[r], accv[m][r], 0, 0, 0);
            }
        }
    }

    // epilogue: eh = sum_oc w_eh[oc]*relu(acc + b_ec[oc]);  cv written raw (f32).
    float we[4][4], be[4][4];
    #pragma unroll
    for (int m = 0; m < 4; ++m)
        #pragma unroll
        for (int q = 0; q < 4; ++q) {
            int oc = m * 16 + 4 * g + q;
            we[m][q] = w_eh[oc];
            be[m][q] = b_ec[oc];
        }
    #pragma unroll
    for (int r = 0; r < 4; ++r) {
        float p = 0.f;
        #pragma unroll
        for (int m = 0; m < 4; ++m)
            #pragma unroll
            for (int q = 0; q < 4; ++q)
                p += we[m][q] * fmaxf(acc[m][r][q] + be[m][q], 0.f);
        p += __shfl_xor(p, 16);
        p += __shfl_xor(p, 32);
        const int gpix = (ty0 + 4 * wv + r) * WC_ + tx0 + j;
        if (g == 0)
            eh_out[(size_t)b * (HC_ * WC_) + gpix] = p;
        float* cvp = cvb + ((size_t)b * (HC_ * WC_) + gpix) * 20;
        #pragma unroll
        for (int m = 0; m < 2; ++m)
            #pragma unroll
            for (int q = 0; q < 4; ++q) {
                int ov = m * 16 + 4 * g + q;
                if (ov < COUT_) cvp[ov] = accv[m][r][q];
            }
    }
}

// ---------------- K_fine: fused fine stage ----------------
__global__ __launch_bounds__(256) void k_fine(
    const float* __restrict__ raw,
    const float* __restrict__ w_ef, const float* __restrict__ b_ef,
    const float* __restrict__ w_eh,
    const float* __restrict__ w_q_t, const float* __restrict__ b_q,
    const unsigned short* __restrict__ Avq,
    const float* __restrict__ b_v,
    const float* __restrict__ eh_g,          // (B,9216)
    const float* __restrict__ cvb,           // (B,9216,20)
    float* __restrict__ out_y,
    float* __restrict__ out_ne)
{
    __shared__ unsigned short sQ[336 * 72];   // 72-half stride: 16B aligned b128, 2-way banks
    __shared__ unsigned short sV[324 * 20];
    __shared__ float sNE[324];

    const int tid = threadIdx.x;
    const int b   = blockIdx.z;
    const int ty0 = blockIdx.y * 16;
    const int tx0 = blockIdx.x * 16;
    const float* rb = raw + (size_t)b * 3 * (HF_ * WF_);

    // Phase 1: per halo pixel: ef, non_edge, q -> sQ (bf16)
    for (int p = tid; p < 324; p += 256) {
        const int iy = p / 18, ix = p - iy * 18;
        const int gh = ty0 + iy - 1, gw = tx0 + ix - 1;
        unsigned int* qrow = (unsigned int*)&sQ[p * 72];
        if (gh < 0 || gh >= HF_ || gw < 0 || gw >= WF_) {
            #pragma unroll
            for (int c2 = 0; c2 < 32; ++c2) qrow[c2] = 0u;
            sNE[p] = 0.f;
            continue;
        }
        float r[3][9];
        #pragma unroll
        for (int dy = 0; dy < 3; ++dy) {
            #pragma unroll
            for (int dx = 0; dx < 3; ++dx) {
                int hh = gh + dy - 1, ww = gw + dx - 1;
                bool ok = (hh >= 0) & (hh < HF_) & (ww >= 0) & (ww < WF_);
                size_t off = (size_t)hh * WF_ + ww;
                #pragma unroll
                for (int ci = 0; ci < 3; ++ci)
                    r[ci][dy * 3 + dx] = ok ? rb[(size_t)ci * (HF_ * WF_) + off] : 0.f;
            }
        }
        float ef = b_ef[0];
        #pragma unroll
        for (int ci = 0; ci < 3; ++ci)
            #pragma unroll
            for (int t = 0; t < 9; ++t)
                ef = fmaf(w_ef[ci * 9 + t], r[ci][t], ef);
        ef = fmaxf(ef, 0.f);

        const int cpix = (gh >> 2) * WC_ + (gw >> 2);
        float logit = eh_g[(size_t)b * (HC_ * WC_) + cpix] + w_eh[64] * ef;
        float ne = 1.f / (1.f + __expf(-logit));
        sNE[p] = ne;

        float q[64];
        const float r0 = r[0][4], r1 = r[1][4], r2 = r[2][4];
        #pragma unroll
        for (int oc = 0; oc < 64; ++oc) {
            float t = fmaf(w_q_t[oc], r0, b_q[oc]);
            t = fmaf(w_q_t[64 + oc], r1, t);
            q[oc] = fmaf(w_q_t[128 + oc], r2, t);
        }
        #pragma unroll
        for (int c2 = 0; c2 < 32; ++c2)
            qrow[c2] = (unsigned int)f2bf(q[2 * c2]) | ((unsigned int)f2bf(q[2 * c2 + 1]) << 16);
    }
    __syncthreads();

    // Phase 1.5: V = Wvq(19x64) @ Q + cv + b_v via MFMA (21 px-groups x 2 m-tiles)
    {
        const int lane = tid & 63;
        const int wv   = tid >> 6;
        const int jl   = lane & 15, g = lane >> 4;
        const bf16x8* Aq = (const bf16x8*)Avq;
        for (int t = wv; t < 42; t += 4) {
            const int grp = t >> 1, m = t & 1;
            f32x4 va = (f32x4)0.f;
            #pragma unroll
            for (int ckk = 0; ckk < 2; ++ckk) {
                bf16x8 a  = Aq[(ckk * 2 + m) * 64 + lane];
                bf16x8 bq = *(const bf16x8*)&sQ[(grp * 16 + jl) * 72 + ckk * 32 + g * 8];
                va = __builtin_amdgcn_mfma_f32_16x16x32_bf16(a, bq, va, 0, 0, 0);
            }
            const int px = grp * 16 + jl;
            if (px < 324) {
                const int iy = px / 18, ix = px - iy * 18;
                const int gh = ty0 + iy - 1, gw = tx0 + ix - 1;
                const bool inr = (gh >= 0) & (gh < HF_) & (gw >= 0) & (gw < WF_);
                size_t cvoff = 0;
                if (inr) cvoff = ((size_t)b * (HC_ * WC_) + (gh >> 2) * WC_ + (gw >> 2)) * 20;
                #pragma unroll
                for (int q = 0; q < 4; ++q) {
                    int ov = m * 16 + 4 * g + q;
                    if (ov < COUT_) {
                        float vv = inr ? (va[q] + cvb[cvoff + ov] + b_v[ov]) : 0.f;
                        sV[px * 20 + ov] = f2bf(vv);
                    }
                }
            }
        }
    }
    __syncthreads();

    // Phase 2: local attention
    const int py = tid >> 4, px2 = tid & 15;
    const int pown = (py + 1) * 18 + (px2 + 1);

    float qs[64];
    {
        const unsigned int* qp = (const unsigned int*)&sQ[pown * 72];
        #pragma unroll
        for (int c2 = 0; c2 < 32; ++c2) {
            unsigned int u = qp[c2];
            qs[2 * c2]     = bflo(u);
            qs[2 * c2 + 1] = bfhi(u);
        }
    }
    float sc[9];
    #pragma unroll
    for (int k = 0; k < 9; ++k) {
        const int pn = pown + (k / 3 - 1) * 18 + (k % 3 - 1);
        const unsigned int* qp = (const unsigned int*)&sQ[pn * 72];
        float d = 0.f;
        #pragma unroll
        for (int c2 = 0; c2 < 32; ++c2) {
            unsigned int u = qp[c2];
            d = fmaf(qs[2 * c2], bflo(u), d);
            d = fmaf(qs[2 * c2 + 1], bfhi(u), d);
        }
        sc[k] = sNE[pn] * d;
    }
    float mmax = sc[0];
    #pragma unroll
    for (int k = 1; k < 9; ++k) mmax = fmaxf(mmax, sc[k]);
    float e[9];
    float ssum = 0.f;
    #pragma unroll
    for (int k = 0; k < 9; ++k) { e[k] = __expf(sc[k] - mmax); ssum += e[k]; }
    const float inv = 1.f / ssum;

    float y[COUT_];
    #pragma unroll
    for (int ov = 0; ov < COUT_; ++ov) y[ov] = 0.f;
    #pragma unroll
    for (int k = 0; k < 9; ++k) {
        const int pn = pown + (k / 3 - 1) * 18 + (k % 3 - 1);
        const float a = e[k] * inv;
        const unsigned int* vp = (const unsigned int*)&sV[pn * 20];
        #pragma unroll
        for (int o2 = 0; o2 < 9; ++o2) {
            unsigned int u = vp[o2];
            y[2 * o2]     = fmaf(a, bflo(u), y[2 * o2]);
            y[2 * o2 + 1] = fmaf(a, bfhi(u), y[2 * o2 + 1]);
        }
        y[18] = fmaf(a, bflo((unsigned int)sV[pn * 20 + 18]), y[18]);
    }

    const int gh = ty0 + py, gw = tx0 + px2;
    const size_t ppos = (size_t)gh * WF_ + gw;
    #pragma unroll
    for (int ov = 0; ov < COUT_; ++ov)
        out_y[((size_t)b * COUT_ + ov) * (HF_ * WF_) + ppos] = y[ov];
    out_ne[(size_t)b * (HF_ * WF_) + ppos] = sNE[pown];
}

// ---------------- launch ----------------
extern "C" void kernel_launch(void* const* d_in, const int* in_sizes, int n_in,
                              void* d_out, int out_size, void* d_ws, size_t ws_size,
                              hipStream_t stream)
{
    const float* coarse = (const float*)d_in[0];
    const float* raw    = (const float*)d_in[1];
    const float* w_ef   = (const float*)d_in[2];
    const float* b_ef   = (const float*)d_in[3];
    const float* w_ec   = (const float*)d_in[4];
    const float* b_ec   = (const float*)d_in[5];
    const float* w_eh   = (const float*)d_in[6];
    const float* w_q    = (const float*)d_in[7];
    const float* b_q    = (const float*)d_in[8];
    const float* w_v    = (const float*)d_in[9];
    const float* b_v    = (const float*)d_in[10];
    (void)in_sizes; (void)n_in; (void)out_size; (void)ws_size;

    unsigned char* ws = (unsigned char*)d_ws;
    const size_t XT_BYTES = (size_t)B_ * 98 * 98 * 256 * 2;   // 9,834,496
    unsigned short* Xt    = (unsigned short*)ws;
    unsigned short* A_pk  = (unsigned short*)(ws + XT_BYTES);                 // 294,912 B
    unsigned short* Avc   = (unsigned short*)(ws + XT_BYTES + 294912);        // 16,384 B
    unsigned short* Avq   = (unsigned short*)(ws + XT_BYTES + 294912 + 16384);// 4,096 B
    float* w_q_t  = (float*)(ws + XT_BYTES + 294912 + 16384 + 4096);          // 768 B
    float* eh     = (float*)(ws + XT_BYTES + 294912 + 16384 + 4096 + 768);    // 73,728 B
    float* cvb    = (float*)(ws + XT_BYTES + 294912 + 16384 + 4096 + 768 + 73728); // 1,474,560 B

    float* out_y  = (float*)d_out;
    float* out_ne = out_y + (size_t)B_ * COUT_ * HF_ * WF_;

    hipMemsetAsync(Xt, 0, XT_BYTES, stream);
    hipLaunchKernelGGL(k_prep, dim3(576), dim3(256), 0, stream,
                       w_ec, w_v, w_q, A_pk, Avc, Avq, w_q_t);
    hipLaunchKernelGGL(k_xt, dim3(36, B_), dim3(256), 0, stream, coarse, Xt);
    hipLaunchKernelGGL(k_ec, dim3(6, 6, B_), dim3(256), 0, stream,
                       Xt, A_pk, Avc, b_ec, w_eh, eh, cvb);
    hipLaunchKernelGGL(k_fine, dim3(24, 24, B_), dim3(256), 0, stream,
                       raw, w_ef, b_ef, w_eh, w_q_t, b_q, Avq, b_v,
                       eh, cvb, out_y, out_ne);
}

// Round 5
// 113.783 us; speedup vs baseline: 2.6478x; 1.2955x over previous
//
#include <hip/hip_runtime.h>
#include <math.h>

#define B_    2
#define HC_   96
#define WC_   96
#define HF_   384
#define WF_   384
#define CINC_ 256
#define CH_   64
#define COUT_ 19

typedef __attribute__((ext_vector_type(8))) short bf16x8;
typedef __attribute__((ext_vector_type(4))) float f32x4;

__device__ __forceinline__ unsigned short f2bf(float f) {
    unsigned int u = __float_as_uint(f);
    u += 0x7fffu + ((u >> 16) & 1u);
    return (unsigned short)(u >> 16);
}
__device__ __forceinline__ unsigned int pk2(float a, float b) {
    return (unsigned int)f2bf(a) | ((unsigned int)f2bf(b) << 16);
}
__device__ __forceinline__ float bflo(unsigned int u) { return __uint_as_float(u << 16); }
__device__ __forceinline__ float bfhi(unsigned int u) { return __uint_as_float(u & 0xffff0000u); }

// ---------------- K0: weight prep ----------------
// A_pk  (9,8,4,64,8) bf16 : ec weights in 16x16x32 A-frag layout
// Avc   (8,2,64,8) bf16 : w_v[:, :256];  Avq (2,2,64,8) : w_v[:, 256:320]
// w_q_t (3,64) f32
__global__ __launch_bounds__(256) void k_prep(
    const float* __restrict__ w_ec, const float* __restrict__ w_v,
    const float* __restrict__ w_q,
    unsigned short* __restrict__ A_pk, unsigned short* __restrict__ Avc,
    unsigned short* __restrict__ Avq, float* __restrict__ w_q_t)
{
    int i = blockIdx.x * 256 + threadIdx.x;
    if (i < 147456) {
        int e = i & 7, l = (i >> 3) & 63, m = (i >> 9) & 3, ck = (i >> 11) & 7, tap = i >> 14;
        int oc = m * 16 + (l & 15);
        int ch = ck * 32 + (l >> 4) * 8 + e;
        A_pk[i] = f2bf(w_ec[(oc * 256 + ch) * 9 + tap]);
    }
    if (i < 8192) {
        int e = i & 7, l = (i >> 3) & 63, m = (i >> 9) & 1, ck = (i >> 10) & 7;
        int ov = m * 16 + (l & 15);
        int ch = ck * 32 + (l >> 4) * 8 + e;
        Avc[i] = (ov < COUT_) ? f2bf(w_v[ov * 320 + ch]) : (unsigned short)0;
    }
    if (i < 2048) {
        int e = i & 7, l = (i >> 3) & 63, m = (i >> 9) & 1, ck = (i >> 10) & 1;
        int ov = m * 16 + (l & 15);
        int ch = 256 + ck * 32 + (l >> 4) * 8 + e;
        Avq[i] = (ov < COUT_) ? f2bf(w_v[ov * 320 + ch]) : (unsigned short)0;
    }
    if (i < 192) {
        int oc = i / 3, ci = i - oc * 3;
        w_q_t[ci * 64 + oc] = w_q[i];
    }
}

// ---------------- K_zero: zero the 1-px border of Xt ----------------
__global__ __launch_bounds__(256) void k_zero(unsigned short* __restrict__ Xt)
{
    int e = blockIdx.x * 256 + threadIdx.x;
    if (e >= 388 * B_) return;
    int b = e / 388, i = e - b * 388;
    int gy, gx;
    if (i < 98)       { gy = 0;           gx = i; }
    else if (i < 196) { gy = 97;          gx = i - 98; }
    else if (i < 292) { gy = i - 196 + 1; gx = 0; }
    else              { gy = i - 292 + 1; gx = 97; }
    uint4* dst = (uint4*)(Xt + (((size_t)(b * 98 + gy)) * 98 + gx) * 256);
    uint4 zz; zz.x = zz.y = zz.z = zz.w = 0u;
    #pragma unroll
    for (int c = 0; c < 32; ++c) dst[c] = zz;
}

// ---------------- K_xt: coarse (B,256,96,96) f32 -> Xt (B,98,98,256) bf16 ----------------
__global__ __launch_bounds__(256) void k_xt(
    const float* __restrict__ x, unsigned short* __restrict__ Xt)
{
    const int b  = blockIdx.y;
    const int cz = blockIdx.z * 64;
    const int px = blockIdx.x * 256 + threadIdx.x;      // 0..9215
    const int gy = px / 96, gx = px - gy * 96;
    const float* src = x + (size_t)b * CINC_ * 9216;
    unsigned short* dst = Xt + (((size_t)(b * 98 + gy + 1)) * 98 + gx + 1) * 256;
    for (int c0 = cz; c0 < cz + 64; c0 += 8) {
        float f[8];
        #pragma unroll
        for (int t = 0; t < 8; ++t) f[t] = src[(size_t)(c0 + t) * 9216 + px];
        uint4 u;
        u.x = pk2(f[0], f[1]);
        u.y = pk2(f[2], f[3]);
        u.z = pk2(f[4], f[5]);
        u.w = pk2(f[6], f[7]);
        *(uint4*)&dst[c0] = u;
    }
}

// ---------------- K_ec: MFMA conv3x3 (ec partial over 16 oc) + cv GEMM (z==0) --------
// grid (6, 12, 4*B): 16x8 px tile, oc-quarter z. 4 waves; wave wv: rows 2wv..2wv+1.
__global__ __launch_bounds__(256, 2) void k_ec(
    const unsigned short* __restrict__ Xt,
    const unsigned short* __restrict__ A_pk,
    const unsigned short* __restrict__ Avc,
    const float* __restrict__ b_ec, const float* __restrict__ w_eh,
    float* __restrict__ eh_part,         // (4,B,9216)
    float* __restrict__ cvb)             // (B,9216,20)
{
    __shared__ unsigned short sB[180 * 40];   // 10x18 halo px, 32ch chunk (80B stride)

    const int tid  = threadIdx.x;
    const int lane = tid & 63;
    const int wv   = tid >> 6;
    const int j    = lane & 15;
    const int g    = lane >> 4;
    const int zb   = blockIdx.z;
    const int z    = zb & 3;
    const int b    = zb >> 2;
    const int ty0  = blockIdx.y * 8;
    const int tx0  = blockIdx.x * 16;

    f32x4 acc[2];
    f32x4 accv[2][2];
    acc[0] = acc[1] = (f32x4)0.f;
    accv[0][0] = accv[0][1] = accv[1][0] = accv[1][1] = (f32x4)0.f;

    const bf16x8* Af  = (const bf16x8*)A_pk;
    const bf16x8* Avf = (const bf16x8*)Avc;

    for (int ck = 0; ck < 8; ++ck) {
        __syncthreads();
        for (int i = tid; i < 720; i += 256) {
            int px = i >> 2, part = i & 3;
            int ty = px / 18, tx = px - ty * 18;
            const unsigned short* src = Xt
                + (((size_t)(b * 98 + ty0 + ty)) * 98 + (tx0 + tx)) * 256
                + ck * 32 + part * 8;
            *(uint4*)&sB[px * 40 + part * 8] = *(const uint4*)src;
        }
        __syncthreads();

        #pragma unroll
        for (int tap = 0; tap < 9; ++tap) {
            const int dy = tap / 3, dx = tap % 3;
            bf16x8 b0 = *(const bf16x8*)&sB[((2 * wv + 0 + dy) * 18 + (j + dx)) * 40 + g * 8];
            bf16x8 b1 = *(const bf16x8*)&sB[((2 * wv + 1 + dy) * 18 + (j + dx)) * 40 + g * 8];
            bf16x8 a  = Af[((tap * 8 + ck) * 4 + z) * 64 + lane];
            acc[0] = __builtin_amdgcn_mfma_f32_16x16x32_bf16(a, b0, acc[0], 0, 0, 0);
            acc[1] = __builtin_amdgcn_mfma_f32_16x16x32_bf16(a, b1, acc[1], 0, 0, 0);
            if (z == 0 && tap == 4) {
                bf16x8 av0 = Avf[(ck * 2 + 0) * 64 + lane];
                bf16x8 av1 = Avf[(ck * 2 + 1) * 64 + lane];
                accv[0][0] = __builtin_amdgcn_mfma_f32_16x16x32_bf16(av0, b0, accv[0][0], 0, 0, 0);
                accv[0][1] = __builtin_amdgcn_mfma_f32_16x16x32_bf16(av0, b1, accv[0][1], 0, 0, 0);
                accv[1][0] = __builtin_amdgcn_mfma_f32_16x16x32_bf16(av1, b0, accv[1][0], 0, 0, 0);
                accv[1][1] = __builtin_amdgcn_mfma_f32_16x16x32_bf16(av1, b1, accv[1][1], 0, 0, 0);
            }
        }
    }

    float we[4], be[4];
    #pragma unroll
    for (int q = 0; q < 4; ++q) {
        int oc = z * 16 + 4 * g + q;
        we[q] = w_eh[oc];
        be[q] = b_ec[oc];
    }
    #pragma unroll
    for (int r = 0; r < 2; ++r) {
        float p = 0.f;
        #pragma unroll
        for (int q = 0; q < 4; ++q)
            p += we[q] * fmaxf(acc[r][q] + be[q], 0.f);
        p += __shfl_xor(p, 16);
        p += __shfl_xor(p, 32);
        const int gpix = (ty0 + 2 * wv + r) * WC_ + tx0 + j;
        if (g == 0)
            eh_part[((size_t)z * B_ + b) * (HC_ * WC_) + gpix] = p;
        if (z == 0) {
            float* cvp = cvb + ((size_t)b * (HC_ * WC_) + gpix) * 20;
            #pragma unroll
            for (int m = 0; m < 2; ++m)
                #pragma unroll
                for (int q = 0; q < 4; ++q) {
                    int ov = m * 16 + 4 * g + q;
                    if (ov < COUT_) cvp[ov] = accv[m][r][q];
                }
        }
    }
}

// ---------------- K_fine: fused fine stage ----------------
__global__ __launch_bounds__(256) void k_fine(
    const float* __restrict__ raw,
    const float* __restrict__ w_ef, const float* __restrict__ b_ef,
    const float* __restrict__ w_eh,
    const float* __restrict__ w_q_t, const float* __restrict__ b_q,
    const unsigned short* __restrict__ Avq,
    const float* __restrict__ b_v,
    const float* __restrict__ eh_g,          // (4,B,9216)
    const float* __restrict__ cvb,           // (B,9216,20)
    float* __restrict__ out_y,
    float* __restrict__ out_ne)
{
    __shared__ unsigned short sQ[336 * 72];   // bf16, 144B row stride (b128-aligned)
    __shared__ unsigned short sV[324 * 20];   // [0..18]=v bf16, [19]=non_edge bf16
    __shared__ float sRaw[3][20][20];         // raw tile + 2-px halo, zero-padded

    const int tid = threadIdx.x;
    const int b   = blockIdx.z;
    const int ty0 = blockIdx.y * 16;
    const int tx0 = blockIdx.x * 16;
    const float* rb = raw + (size_t)b * 3 * (HF_ * WF_);

    // Phase 0: stage raw 20x20x3 (zero-padded)
    for (int i = tid; i < 1200; i += 256) {
        int ch = i / 400, rem = i - ch * 400;
        int ry = rem / 20, rx = rem - ry * 20;
        int gh = ty0 + ry - 2, gw = tx0 + rx - 2;
        float v = 0.f;
        if (gh >= 0 && gh < HF_ && gw >= 0 && gw < WF_)
            v = rb[(size_t)ch * (HF_ * WF_) + gh * WF_ + gw];
        sRaw[ch][ry][rx] = v;
    }
    __syncthreads();

    // Phase 1: per halo pixel: ef, non_edge, q -> sQ (bf16, b128 writes)
    for (int p = tid; p < 324; p += 256) {
        const int iy = p / 18, ix = p - iy * 18;
        const int gh = ty0 + iy - 1, gw = tx0 + ix - 1;
        uint4* qrow4 = (uint4*)&sQ[p * 72];
        if (gh < 0 || gh >= HF_ || gw < 0 || gw >= WF_) {
            uint4 zz; zz.x = zz.y = zz.z = zz.w = 0u;
            #pragma unroll
            for (int c4 = 0; c4 < 8; ++c4) qrow4[c4] = zz;
            sV[p * 20 + 19] = 0;
            continue;
        }
        float r[3][9];
        #pragma unroll
        for (int ci = 0; ci < 3; ++ci)
            #pragma unroll
            for (int dy = 0; dy < 3; ++dy)
                #pragma unroll
                for (int dx = 0; dx < 3; ++dx)
                    r[ci][dy * 3 + dx] = sRaw[ci][iy + dy][ix + dx];

        float ef = b_ef[0];
        #pragma unroll
        for (int ci = 0; ci < 3; ++ci)
            #pragma unroll
            for (int t = 0; t < 9; ++t)
                ef = fmaf(w_ef[ci * 9 + t], r[ci][t], ef);
        ef = fmaxf(ef, 0.f);

        const int cpix = (gh >> 2) * WC_ + (gw >> 2);
        float logit = w_eh[64] * ef;
        #pragma unroll
        for (int zz = 0; zz < 4; ++zz)
            logit += eh_g[((size_t)zz * B_ + b) * (HC_ * WC_) + cpix];
        float ne = 1.f / (1.f + __expf(-logit));
        sV[p * 20 + 19] = f2bf(ne);

        float q[64];
        const float r0 = r[0][4], r1 = r[1][4], r2 = r[2][4];
        #pragma unroll
        for (int oc = 0; oc < 64; ++oc) {
            float t = fmaf(w_q_t[oc], r0, b_q[oc]);
            t = fmaf(w_q_t[64 + oc], r1, t);
            q[oc] = fmaf(w_q_t[128 + oc], r2, t);
        }
        #pragma unroll
        for (int c4 = 0; c4 < 8; ++c4) {
            uint4 u;
            u.x = pk2(q[8 * c4 + 0], q[8 * c4 + 1]);
            u.y = pk2(q[8 * c4 + 2], q[8 * c4 + 3]);
            u.z = pk2(q[8 * c4 + 4], q[8 * c4 + 5]);
            u.w = pk2(q[8 * c4 + 6], q[8 * c4 + 7]);
            qrow4[c4] = u;
        }
    }
    __syncthreads();

    // Phase 1.5: V = Wvq(19x64) @ Q + cv + b_v via MFMA
    {
        const int lane = tid & 63;
        const int wv   = tid >> 6;
        const int jl   = lane & 15, g = lane >> 4;
        const bf16x8* Aq = (const bf16x8*)Avq;
        for (int t = wv; t < 42; t += 4) {
            const int grp = t >> 1, m = t & 1;
            f32x4 va = (f32x4)0.f;
            #pragma unroll
            for (int ckk = 0; ckk < 2; ++ckk) {
                bf16x8 a  = Aq[(ckk * 2 + m) * 64 + lane];
                bf16x8 bq = *(const bf16x8*)&sQ[(grp * 16 + jl) * 72 + ckk * 32 + g * 8];
                va = __builtin_amdgcn_mfma_f32_16x16x32_bf16(a, bq, va, 0, 0, 0);
            }
            const int px = grp * 16 + jl;
            if (px < 324) {
                const int iy = px / 18, ix = px - iy * 18;
                const int gh = ty0 + iy - 1, gw = tx0 + ix - 1;
                const bool inr = (gh >= 0) & (gh < HF_) & (gw >= 0) & (gw < WF_);
                size_t cvoff = 0;
                if (inr) cvoff = ((size_t)b * (HC_ * WC_) + (gh >> 2) * WC_ + (gw >> 2)) * 20;
                #pragma unroll
                for (int q = 0; q < 4; ++q) {
                    int ov = m * 16 + 4 * g + q;
                    if (ov < COUT_) {
                        float vv = inr ? (va[q] + cvb[cvoff + ov] + b_v[ov]) : 0.f;
                        sV[px * 20 + ov] = f2bf(vv);
                    }
                }
            }
        }
    }
    __syncthreads();

    // Phase 2: local attention (all sQ reads as b128)
    const int py = tid >> 4, px2 = tid & 15;
    const int pown = (py + 1) * 18 + (px2 + 1);

    float qs[64];
    {
        const uint4* qp4 = (const uint4*)&sQ[pown * 72];
        #pragma unroll
        for (int c4 = 0; c4 < 8; ++c4) {
            uint4 u = qp4[c4];
            qs[8 * c4 + 0] = bflo(u.x); qs[8 * c4 + 1] = bfhi(u.x);
            qs[8 * c4 + 2] = bflo(u.y); qs[8 * c4 + 3] = bfhi(u.y);
            qs[8 * c4 + 4] = bflo(u.z); qs[8 * c4 + 5] = bfhi(u.z);
            qs[8 * c4 + 6] = bflo(u.w); qs[8 * c4 + 7] = bfhi(u.w);
        }
    }
    float sc[9];
    #pragma unroll
    for (int k = 0; k < 9; ++k) {
        const int pn = pown + (k / 3 - 1) * 18 + (k % 3 - 1);
        const uint4* qp4 = (const uint4*)&sQ[pn * 72];
        float d = 0.f;
        #pragma unroll
        for (int c4 = 0; c4 < 8; ++c4) {
            uint4 u = qp4[c4];
            d = fmaf(qs[8 * c4 + 0], bflo(u.x), d);
            d = fmaf(qs[8 * c4 + 1], bfhi(u.x), d);
            d = fmaf(qs[8 * c4 + 2], bflo(u.y), d);
            d = fmaf(qs[8 * c4 + 3], bfhi(u.y), d);
            d = fmaf(qs[8 * c4 + 4], bflo(u.z), d);
            d = fmaf(qs[8 * c4 + 5], bfhi(u.z), d);
            d = fmaf(qs[8 * c4 + 6], bflo(u.w), d);
            d = fmaf(qs[8 * c4 + 7], bfhi(u.w), d);
        }
        float ne = bflo((unsigned int)sV[pn * 20 + 19]);
        sc[k] = ne * d;
    }
    float mmax = sc[0];
    #pragma unroll
    for (int k = 1; k < 9; ++k) mmax = fmaxf(mmax, sc[k]);
    float e[9];
    float ssum = 0.f;
    #pragma unroll
    for (int k = 0; k < 9; ++k) { e[k] = __expf(sc[k] - mmax); ssum += e[k]; }
    const float inv = 1.f / ssum;

    float y[COUT_];
    #pragma unroll
    for (int ov = 0; ov < COUT_; ++ov) y[ov] = 0.f;
    #pragma unroll
    for (int k = 0; k < 9; ++k) {
        const int pn = pown + (k / 3 - 1) * 18 + (k % 3 - 1);
        const float a = e[k] * inv;
        const unsigned int* vp = (const unsigned int*)&sV[pn * 20];
        #pragma unroll
        for (int o2 = 0; o2 < 9; ++o2) {
            unsigned int u = vp[o2];
            y[2 * o2]     = fmaf(a, bflo(u), y[2 * o2]);
            y[2 * o2 + 1] = fmaf(a, bfhi(u), y[2 * o2 + 1]);
        }
        y[18] = fmaf(a, bflo((unsigned int)sV[pn * 20 + 18]), y[18]);
    }

    const int gh = ty0 + py, gw = tx0 + px2;
    const size_t ppos = (size_t)gh * WF_ + gw;
    #pragma unroll
    for (int ov = 0; ov < COUT_; ++ov)
        out_y[((size_t)b * COUT_ + ov) * (HF_ * WF_) + ppos] = y[ov];
    out_ne[(size_t)b * (HF_ * WF_) + ppos] = bflo((unsigned int)sV[pown * 20 + 19]);
}

// ---------------- launch ----------------
extern "C" void kernel_launch(void* const* d_in, const int* in_sizes, int n_in,
                              void* d_out, int out_size, void* d_ws, size_t ws_size,
                              hipStream_t stream)
{
    const float* coarse = (const float*)d_in[0];
    const float* raw    = (const float*)d_in[1];
    const float* w_ef   = (const float*)d_in[2];
    const float* b_ef   = (const float*)d_in[3];
    const float* w_ec   = (const float*)d_in[4];
    const float* b_ec   = (const float*)d_in[5];
    const float* w_eh   = (const float*)d_in[6];
    const float* w_q    = (const float*)d_in[7];
    const float* b_q    = (const float*)d_in[8];
    const float* w_v    = (const float*)d_in[9];
    const float* b_v    = (const float*)d_in[10];
    (void)in_sizes; (void)n_in; (void)out_size; (void)ws_size;

    unsigned char* ws = (unsigned char*)d_ws;
    const size_t XT_BYTES = (size_t)B_ * 98 * 98 * 256 * 2;   // 9,834,496
    unsigned short* Xt    = (unsigned short*)ws;
    unsigned short* A_pk  = (unsigned short*)(ws + XT_BYTES);                  // 294,912 B
    unsigned short* Avc   = (unsigned short*)(ws + XT_BYTES + 294912);         // 16,384 B
    unsigned short* Avq   = (unsigned short*)(ws + XT_BYTES + 294912 + 16384); // 4,096 B
    float* w_q_t  = (float*)(ws + XT_BYTES + 294912 + 16384 + 4096);           // 768 B
    float* eh     = (float*)(ws + XT_BYTES + 294912 + 16384 + 4096 + 768);     // 4*B*9216*4 = 294,912 B
    float* cvb    = (float*)(ws + XT_BYTES + 294912 + 16384 + 4096 + 768 + 294912); // 1,474,560 B

    float* out_y  = (float*)d_out;
    float* out_ne = out_y + (size_t)B_ * COUT_ * HF_ * WF_;

    hipLaunchKernelGGL(k_zero, dim3(4), dim3(256), 0, stream, Xt);
    hipLaunchKernelGGL(k_prep, dim3(576), dim3(256), 0, stream,
                       w_ec, w_v, w_q, A_pk, Avc, Avq, w_q_t);
    hipLaunchKernelGGL(k_xt, dim3(36, B_, 4), dim3(256), 0, stream, coarse, Xt);
    hipLaunchKernelGGL(k_ec, dim3(6, 12, 4 * B_), dim3(256), 0, stream,
                       Xt, A_pk, Avc, b_ec, w_eh, eh, cvb);
    hipLaunchKernelGGL(k_fine, dim3(24, 24, B_), dim3(256), 0, stream,
                       raw, w_ef, b_ef, w_eh, w_q_t, b_q, Avq, b_v,
                       eh, cvb, out_y, out_ne);
}

// Round 6
// 101.207 us; speedup vs baseline: 2.9768x; 1.1243x over previous
//
#include <hip/hip_runtime.h>
#include <math.h>

#define B_    2
#define HC_   96
#define WC_   96
#define HF_   384
#define WF_   384
#define CINC_ 256
#define CH_   64
#define COUT_ 19

typedef __attribute__((ext_vector_type(8))) short bf16x8;
typedef __attribute__((ext_vector_type(4))) float f32x4;

__device__ __forceinline__ unsigned short f2bf(float f) {
    unsigned int u = __float_as_uint(f);
    u += 0x7fffu + ((u >> 16) & 1u);
    return (unsigned short)(u >> 16);
}
__device__ __forceinline__ unsigned int pk2(float a, float b) {
    return (unsigned int)f2bf(a) | ((unsigned int)f2bf(b) << 16);
}
__device__ __forceinline__ float bflo(unsigned int u) { return __uint_as_float(u << 16); }
__device__ __forceinline__ float bfhi(unsigned int u) { return __uint_as_float(u & 0xffff0000u); }

// ---------------- K_pre: merged prep + border-zero + transpose ----------------
// bid <576   : weight prep (A_pk, Avc, w_q_t, w_vq_t)
// bid 576-579: zero 1-px border of Xt
// bid 580-867: coarse (B,256,96,96) f32 -> Xt (B,98,98,256) bf16 (interior)
__global__ __launch_bounds__(256) void k_pre(
    const float* __restrict__ x,      // coarse
    const float* __restrict__ w_ec, const float* __restrict__ w_v,
    const float* __restrict__ w_q,
    unsigned short* __restrict__ Xt,
    unsigned short* __restrict__ A_pk, unsigned short* __restrict__ Avc,
    float* __restrict__ w_q_t, float* __restrict__ w_vq_t)
{
    const int bid = blockIdx.x;
    const int tid = threadIdx.x;
    if (bid < 576) {
        int i = bid * 256 + tid;
        // A_pk (9,8,4,64,8): ec weights in 16x16x32 A-frag layout
        {
            int e = i & 7, l = (i >> 3) & 63, m = (i >> 9) & 3, ck = (i >> 11) & 7, tap = i >> 14;
            int oc = m * 16 + (l & 15);
            int ch = ck * 32 + (l >> 4) * 8 + e;
            A_pk[i] = f2bf(w_ec[(oc * 256 + ch) * 9 + tap]);
        }
        if (i < 8192) {  // Avc (8,2,64,8): w_v[:, :256], ov>=19 -> 0
            int e = i & 7, l = (i >> 3) & 63, m = (i >> 9) & 1, ck = (i >> 10) & 7;
            int ov = m * 16 + (l & 15);
            int ch = ck * 32 + (l >> 4) * 8 + e;
            Avc[i] = (ov < COUT_) ? f2bf(w_v[ov * 320 + ch]) : (unsigned short)0;
        }
        if (i < 1280) {  // w_vq_t (64,20) f32: w_v[:, 256:320]^T, ov==19 -> 0
            int c = i / 20, ov = i - c * 20;
            w_vq_t[i] = (ov < COUT_) ? w_v[ov * 320 + 256 + c] : 0.f;
        }
        if (i < 192) {   // w_q_t (3,64) f32
            int oc = i / 3, ci = i - oc * 3;
            w_q_t[ci * 64 + oc] = w_q[i];
        }
        return;
    }
    if (bid < 580) {
        int e = (bid - 576) * 256 + tid;
        if (e >= 388 * B_) return;
        int b = e / 388, i = e - b * 388;
        int gy, gx;
        if (i < 98)       { gy = 0;           gx = i; }
        else if (i < 196) { gy = 97;          gx = i - 98; }
        else if (i < 292) { gy = i - 196 + 1; gx = 0; }
        else              { gy = i - 292 + 1; gx = 97; }
        uint4* dst = (uint4*)(Xt + (((size_t)(b * 98 + gy)) * 98 + gx) * 256);
        uint4 zz; zz.x = zz.y = zz.z = zz.w = 0u;
        #pragma unroll
        for (int c = 0; c < 32; ++c) dst[c] = zz;
        return;
    }
    {
        int u = bid - 580;                 // 0..287
        int bx = u % 36;
        int rb = u / 36;                   // 0..7
        int b  = rb & 1;
        int cz = (rb >> 1) * 64;
        int px = bx * 256 + tid;           // 0..9215
        int gy = px / 96, gx = px - gy * 96;
        const float* src = x + (size_t)b * CINC_ * 9216;
        unsigned short* dst = Xt + (((size_t)(b * 98 + gy + 1)) * 98 + gx + 1) * 256;
        for (int c0 = cz; c0 < cz + 64; c0 += 8) {
            float f[8];
            #pragma unroll
            for (int t = 0; t < 8; ++t) f[t] = src[(size_t)(c0 + t) * 9216 + px];
            uint4 v;
            v.x = pk2(f[0], f[1]);
            v.y = pk2(f[2], f[3]);
            v.z = pk2(f[4], f[5]);
            v.w = pk2(f[6], f[7]);
            *(uint4*)&dst[c0] = v;
        }
    }
}

// ---------------- K_ec: MFMA conv3x3 (ec partial over 16 oc) + cv GEMM (z==0) --------
// grid (6, 12, 4*B): 16x8 px tile, oc-quarter z. 4 waves; wave wv: rows 2wv..2wv+1.
__global__ __launch_bounds__(256, 2) void k_ec(
    const unsigned short* __restrict__ Xt,
    const unsigned short* __restrict__ A_pk,
    const unsigned short* __restrict__ Avc,
    const float* __restrict__ b_ec, const float* __restrict__ w_eh,
    float* __restrict__ eh_part,         // (4,B,9216)
    float* __restrict__ cvb)             // (B,9216,20)
{
    __shared__ unsigned short sB[180 * 40];   // 10x18 halo px, 32ch chunk (80B stride)

    const int tid  = threadIdx.x;
    const int lane = tid & 63;
    const int wv   = tid >> 6;
    const int j    = lane & 15;
    const int g    = lane >> 4;
    const int zb   = blockIdx.z;
    const int z    = zb & 3;
    const int b    = zb >> 2;
    const int ty0  = blockIdx.y * 8;
    const int tx0  = blockIdx.x * 16;

    f32x4 acc[2];
    f32x4 accv[2][2];
    acc[0] = acc[1] = (f32x4)0.f;
    accv[0][0] = accv[0][1] = accv[1][0] = accv[1][1] = (f32x4)0.f;

    const bf16x8* Af  = (const bf16x8*)A_pk;
    const bf16x8* Avf = (const bf16x8*)Avc;

    for (int ck = 0; ck < 8; ++ck) {
        __syncthreads();
        for (int i = tid; i < 720; i += 256) {
            int px = i >> 2, part = i & 3;
            int ty = px / 18, tx = px - ty * 18;
            const unsigned short* src = Xt
                + (((size_t)(b * 98 + ty0 + ty)) * 98 + (tx0 + tx)) * 256
                + ck * 32 + part * 8;
            *(uint4*)&sB[px * 40 + part * 8] = *(const uint4*)src;
        }
        __syncthreads();

        #pragma unroll
        for (int tap = 0; tap < 9; ++tap) {
            const int dy = tap / 3, dx = tap % 3;
            bf16x8 b0 = *(const bf16x8*)&sB[((2 * wv + 0 + dy) * 18 + (j + dx)) * 40 + g * 8];
            bf16x8 b1 = *(const bf16x8*)&sB[((2 * wv + 1 + dy) * 18 + (j + dx)) * 40 + g * 8];
            bf16x8 a  = Af[((tap * 8 + ck) * 4 + z) * 64 + lane];
            acc[0] = __builtin_amdgcn_mfma_f32_16x16x32_bf16(a, b0, acc[0], 0, 0, 0);
            acc[1] = __builtin_amdgcn_mfma_f32_16x16x32_bf16(a, b1, acc[1], 0, 0, 0);
            if (z == 0 && tap == 4) {
                bf16x8 av0 = Avf[(ck * 2 + 0) * 64 + lane];
                bf16x8 av1 = Avf[(ck * 2 + 1) * 64 + lane];
                accv[0][0] = __builtin_amdgcn_mfma_f32_16x16x32_bf16(av0, b0, accv[0][0], 0, 0, 0);
                accv[0][1] = __builtin_amdgcn_mfma_f32_16x16x32_bf16(av0, b1, accv[0][1], 0, 0, 0);
                accv[1][0] = __builtin_amdgcn_mfma_f32_16x16x32_bf16(av1, b0, accv[1][0], 0, 0, 0);
                accv[1][1] = __builtin_amdgcn_mfma_f32_16x16x32_bf16(av1, b1, accv[1][1], 0, 0, 0);
            }
        }
    }

    float we[4], be[4];
    #pragma unroll
    for (int q = 0; q < 4; ++q) {
        int oc = z * 16 + 4 * g + q;
        we[q] = w_eh[oc];
        be[q] = b_ec[oc];
    }
    #pragma unroll
    for (int r = 0; r < 2; ++r) {
        float p = 0.f;
        #pragma unroll
        for (int q = 0; q < 4; ++q)
            p += we[q] * fmaxf(acc[r][q] + be[q], 0.f);
        p += __shfl_xor(p, 16);
        p += __shfl_xor(p, 32);
        const int gpix = (ty0 + 2 * wv + r) * WC_ + tx0 + j;
        if (g == 0)
            eh_part[((size_t)z * B_ + b) * (HC_ * WC_) + gpix] = p;
        if (z == 0) {
            float* cvp = cvb + ((size_t)b * (HC_ * WC_) + gpix) * 20;
            #pragma unroll
            for (int m = 0; m < 2; ++m)
                #pragma unroll
                for (int q = 0; q < 4; ++q) {
                    int ov = m * 16 + 4 * g + q;
                    if (ov < 20) cvp[ov] = accv[m][r][q];   // ov==19 writes 0 (Avc padded)
                }
        }
    }
}

// ---------------- K_fine: fused fine stage (recompute-q, small-LDS) ----------------
// 16x16 tile, 256 threads. LDS: sRaw (f32 raw + 2px halo) + sV (v bf16 + ne at slot 19).
// Phase B recomputes all 9 neighbor q's from sRaw in f32 registers -> scores exact-ish.
__global__ __launch_bounds__(256, 4) void k_fine(
    const float* __restrict__ raw,
    const float* __restrict__ w_ef, const float* __restrict__ b_ef,
    const float* __restrict__ w_eh,
    const float* __restrict__ w_q_t, const float* __restrict__ b_q,
    const float* __restrict__ w_vq_t,
    const float* __restrict__ b_v,
    const float* __restrict__ eh_g,          // (4,B,9216)
    const float* __restrict__ cvb,           // (B,9216,20)
    float* __restrict__ out_y,
    float* __restrict__ out_ne)
{
    __shared__ float sRaw[3][20][20];          // 4.8 KB
    __shared__ unsigned short sV[324 * 24];    // 15.2 KB: [0..18]=v bf16, [19]=ne bf16

    const int tid = threadIdx.x;
    const int b   = blockIdx.z;
    const int ty0 = blockIdx.y * 16;
    const int tx0 = blockIdx.x * 16;
    const float* rb = raw + (size_t)b * 3 * (HF_ * WF_);

    // Phase 0: stage raw 20x20x3 (zero-padded, 2-px halo)
    for (int i = tid; i < 1200; i += 256) {
        int ch = i / 400, rem = i - ch * 400;
        int ry = rem / 20, rx = rem - ry * 20;
        int gh = ty0 + ry - 2, gw = tx0 + rx - 2;
        float v = 0.f;
        if (gh >= 0 && gh < HF_ && gw >= 0 && gw < WF_)
            v = rb[(size_t)ch * (HF_ * WF_) + gh * WF_ + gw];
        sRaw[ch][ry][rx] = v;
    }
    __syncthreads();

    // Phase A: per halo pixel (18x18): ef -> ne ; v = b_v + cv + Wvq.q  -> sV
    for (int p = tid; p < 324; p += 256) {
        const int iy = p / 18, ix = p - iy * 18;
        const int gh = ty0 + iy - 1, gw = tx0 + ix - 1;
        uint4* vrow = (uint4*)&sV[p * 24];
        if (gh < 0 || gh >= HF_ || gw < 0 || gw >= WF_) {
            uint4 zz; zz.x = zz.y = zz.z = zz.w = 0u;
            vrow[0] = zz; vrow[1] = zz; vrow[2] = zz;   // v=0, ne=0
            continue;
        }
        float ef = b_ef[0];
        #pragma unroll
        for (int ci = 0; ci < 3; ++ci)
            #pragma unroll
            for (int t = 0; t < 9; ++t)
                ef = fmaf(w_ef[ci * 9 + t], sRaw[ci][iy + t / 3][ix + t % 3], ef);
        ef = fmaxf(ef, 0.f);

        const int cpix = (gh >> 2) * WC_ + (gw >> 2);
        float logit = w_eh[64] * ef;
        #pragma unroll
        for (int zz = 0; zz < 4; ++zz)
            logit += eh_g[((size_t)zz * B_ + b) * (HC_ * WC_) + cpix];
        float ne = 1.f / (1.f + __expf(-logit));

        float v[20];
        {
            const float4* cvp = (const float4*)(cvb + ((size_t)b * (HC_ * WC_) + cpix) * 20);
            float4 c0 = cvp[0], c1 = cvp[1], c2 = cvp[2], c3 = cvp[3], c4 = cvp[4];
            v[0] = c0.x; v[1] = c0.y; v[2] = c0.z; v[3] = c0.w;
            v[4] = c1.x; v[5] = c1.y; v[6] = c1.z; v[7] = c1.w;
            v[8] = c2.x; v[9] = c2.y; v[10] = c2.z; v[11] = c2.w;
            v[12] = c3.x; v[13] = c3.y; v[14] = c3.z; v[15] = c3.w;
            v[16] = c4.x; v[17] = c4.y; v[18] = c4.z;
        }
        #pragma unroll
        for (int ov = 0; ov < COUT_; ++ov) v[ov] += b_v[ov];

        const float r0 = sRaw[0][iy + 1][ix + 1];
        const float r1 = sRaw[1][iy + 1][ix + 1];
        const float r2 = sRaw[2][iy + 1][ix + 1];
        #pragma unroll 4
        for (int c = 0; c < 64; ++c) {
            float qc = fmaf(w_q_t[128 + c], r2,
                       fmaf(w_q_t[64 + c], r1,
                       fmaf(w_q_t[c], r0, b_q[c])));
            #pragma unroll
            for (int ov = 0; ov < COUT_; ++ov)
                v[ov] = fmaf(w_vq_t[c * 20 + ov], qc, v[ov]);
        }
        uint4 u0, u1, u2;
        u0.x = pk2(v[0], v[1]);   u0.y = pk2(v[2], v[3]);
        u0.z = pk2(v[4], v[5]);   u0.w = pk2(v[6], v[7]);
        u1.x = pk2(v[8], v[9]);   u1.y = pk2(v[10], v[11]);
        u1.z = pk2(v[12], v[13]); u1.w = pk2(v[14], v[15]);
        u2.x = pk2(v[16], v[17]); u2.y = pk2(v[18], ne);
        u2.z = 0u; u2.w = 0u;
        vrow[0] = u0; vrow[1] = u1; vrow[2] = u2;
    }
    __syncthreads();

    // Phase B: per own pixel — recompute 9 neighbor q's in f32, scores, softmax, PV
    const int py = tid >> 4, px2 = tid & 15;
    const int iy = py + 1, ix = px2 + 1;
    const int pbase = iy * 18 + ix;

    float rn[3][9];
    #pragma unroll
    for (int ci = 0; ci < 3; ++ci)
        #pragma unroll
        for (int k = 0; k < 9; ++k)
            rn[ci][k] = sRaw[ci][iy + k / 3][ix + k % 3];

    float d[9];
    #pragma unroll
    for (int k = 0; k < 9; ++k) d[k] = 0.f;

    #pragma unroll 2
    for (int c = 0; c < 64; ++c) {
        const float w0 = w_q_t[c], w1 = w_q_t[64 + c], w2 = w_q_t[128 + c];
        const float bq = b_q[c];
        float qn[9];
        #pragma unroll
        for (int k = 0; k < 9; ++k)
            qn[k] = fmaf(w2, rn[2][k], fmaf(w1, rn[1][k], fmaf(w0, rn[0][k], bq)));
        const float qc = qn[4];
        #pragma unroll
        for (int k = 0; k < 9; ++k)
            d[k] = fmaf(qc, qn[k], d[k]);
    }

    float sc[9];
    #pragma unroll
    for (int k = 0; k < 9; ++k) {
        const int pn = pbase + (k / 3 - 1) * 18 + (k % 3 - 1);
        float nek = bflo((unsigned int)sV[pn * 24 + 19]);
        sc[k] = nek * d[k];
    }
    float mmax = sc[0];
    #pragma unroll
    for (int k = 1; k < 9; ++k) mmax = fmaxf(mmax, sc[k]);
    float e[9];
    float ssum = 0.f;
    #pragma unroll
    for (int k = 0; k < 9; ++k) { e[k] = __expf(sc[k] - mmax); ssum += e[k]; }
    const float inv = 1.f / ssum;

    float y[COUT_];
    #pragma unroll
    for (int ov = 0; ov < COUT_; ++ov) y[ov] = 0.f;
    #pragma unroll
    for (int k = 0; k < 9; ++k) {
        const int pn = pbase + (k / 3 - 1) * 18 + (k % 3 - 1);
        const float a = e[k] * inv;
        const unsigned int* vp = (const unsigned int*)&sV[pn * 24];
        #pragma unroll
        for (int o2 = 0; o2 < 9; ++o2) {
            unsigned int u = vp[o2];
            y[2 * o2]     = fmaf(a, bflo(u), y[2 * o2]);
            y[2 * o2 + 1] = fmaf(a, bfhi(u), y[2 * o2 + 1]);
        }
        y[18] = fmaf(a, bflo(vp[9]), y[18]);
    }

    const int gh = ty0 + py, gw = tx0 + px2;
    const size_t ppos = (size_t)gh * WF_ + gw;
    #pragma unroll
    for (int ov = 0; ov < COUT_; ++ov)
        out_y[((size_t)b * COUT_ + ov) * (HF_ * WF_) + ppos] = y[ov];
    out_ne[(size_t)b * (HF_ * WF_) + ppos] = bflo((unsigned int)sV[pbase * 24 + 19]);
}

// ---------------- launch ----------------
extern "C" void kernel_launch(void* const* d_in, const int* in_sizes, int n_in,
                              void* d_out, int out_size, void* d_ws, size_t ws_size,
                              hipStream_t stream)
{
    const float* coarse = (const float*)d_in[0];
    const float* raw    = (const float*)d_in[1];
    const float* w_ef   = (const float*)d_in[2];
    const float* b_ef   = (const float*)d_in[3];
    const float* w_ec   = (const float*)d_in[4];
    const float* b_ec   = (const float*)d_in[5];
    const float* w_eh   = (const float*)d_in[6];
    const float* w_q    = (const float*)d_in[7];
    const float* b_q    = (const float*)d_in[8];
    const float* w_v    = (const float*)d_in[9];
    const float* b_v    = (const float*)d_in[10];
    (void)in_sizes; (void)n_in; (void)out_size; (void)ws_size;

    unsigned char* ws = (unsigned char*)d_ws;
    size_t off = 0;
    unsigned short* Xt    = (unsigned short*)(ws + off); off += (size_t)B_ * 98 * 98 * 256 * 2; // 9,834,496
    unsigned short* A_pk  = (unsigned short*)(ws + off); off += 294912;
    unsigned short* Avc   = (unsigned short*)(ws + off); off += 16384;
    float* w_q_t  = (float*)(ws + off); off += 768;
    float* w_vq_t = (float*)(ws + off); off += 5120;
    float* eh     = (float*)(ws + off); off += (size_t)4 * B_ * 9216 * 4;   // 294,912
    float* cvb    = (float*)(ws + off); off += (size_t)B_ * 9216 * 20 * 4;  // 1,474,560

    float* out_y  = (float*)d_out;
    float* out_ne = out_y + (size_t)B_ * COUT_ * HF_ * WF_;

    hipLaunchKernelGGL(k_pre, dim3(868), dim3(256), 0, stream,
                       coarse, w_ec, w_v, w_q, Xt, A_pk, Avc, w_q_t, w_vq_t);
    hipLaunchKernelGGL(k_ec, dim3(6, 12, 4 * B_), dim3(256), 0, stream,
                       Xt, A_pk, Avc, b_ec, w_eh, eh, cvb);
    hipLaunchKernelGGL(k_fine, dim3(24, 24, B_), dim3(256), 0, stream,
                       raw, w_ef, b_ef, w_eh, w_q_t, b_q, w_vq_t, b_v,
                       eh, cvb, out_y, out_ne);
}

// Round 7
// 63.126 us; speedup vs baseline: 4.7726x; 1.6033x over previous
//
#include <hip/hip_runtime.h>
#include <math.h>

#define B_    2
#define HC_   96
#define WC_   96
#define HF_   384
#define WF_   384
#define CINC_ 256
#define CH_   64
#define COUT_ 19

typedef __attribute__((ext_vector_type(8))) short bf16x8;
typedef __attribute__((ext_vector_type(4))) float f32x4;

__device__ __forceinline__ unsigned short f2bf(float f) {
    unsigned int u = __float_as_uint(f);
    u += 0x7fffu + ((u >> 16) & 1u);
    return (unsigned short)(u >> 16);
}
__device__ __forceinline__ unsigned int pk2(float a, float b) {
    return (unsigned int)f2bf(a) | ((unsigned int)f2bf(b) << 16);
}
__device__ __forceinline__ float bflo(unsigned int u) { return __uint_as_float(u << 16); }
__device__ __forceinline__ float bfhi(unsigned int u) { return __uint_as_float(u & 0xffff0000u); }

// ---------------- K_pre: merged prep + border-zero + transpose + derived weights ----
// bid <576   : weight prep (A_pk, Avc)
// bid 576-579: zero 1-px border of Xt
// bid 580-867: coarse (B,256,96,96) f32 -> Xt (B,98,98,256) bf16 (interior)
// bid 868    : derived weights drv[89]:
//   [0..8]  G[ci*3+cj] = sum_c w_q[c,ci]*w_q[c,cj]
//   [9..11] u[ci]      = sum_c w_q[c,ci]*b_q[c]
//   [12]    s          = b_q . b_q
//   [13+ci*19+ov] M    = sum_c w_v[ov,256+c]*w_q[c,ci]      (19x3)
//   [70+ov] bc         = b_v[ov] + sum_c w_v[ov,256+c]*b_q[c]
__global__ __launch_bounds__(256) void k_pre(
    const float* __restrict__ x,      // coarse
    const float* __restrict__ w_ec, const float* __restrict__ w_v,
    const float* __restrict__ w_q,  const float* __restrict__ b_q,
    const float* __restrict__ b_v,
    unsigned short* __restrict__ Xt,
    unsigned short* __restrict__ A_pk, unsigned short* __restrict__ Avc,
    float* __restrict__ drv)
{
    const int bid = blockIdx.x;
    const int tid = threadIdx.x;
    if (bid < 576) {
        int i = bid * 256 + tid;
        // A_pk (9,8,4,64,8): ec weights in 16x16x32 A-frag layout
        {
            int e = i & 7, l = (i >> 3) & 63, m = (i >> 9) & 3, ck = (i >> 11) & 7, tap = i >> 14;
            int oc = m * 16 + (l & 15);
            int ch = ck * 32 + (l >> 4) * 8 + e;
            A_pk[i] = f2bf(w_ec[(oc * 256 + ch) * 9 + tap]);
        }
        if (i < 8192) {  // Avc (8,2,64,8): w_v[:, :256], ov>=19 -> 0
            int e = i & 7, l = (i >> 3) & 63, m = (i >> 9) & 1, ck = (i >> 10) & 7;
            int ov = m * 16 + (l & 15);
            int ch = ck * 32 + (l >> 4) * 8 + e;
            Avc[i] = (ov < COUT_) ? f2bf(w_v[ov * 320 + ch]) : (unsigned short)0;
        }
        return;
    }
    if (bid < 580) {
        int e = (bid - 576) * 256 + tid;
        if (e >= 388 * B_) return;
        int b = e / 388, i = e - b * 388;
        int gy, gx;
        if (i < 98)       { gy = 0;           gx = i; }
        else if (i < 196) { gy = 97;          gx = i - 98; }
        else if (i < 292) { gy = i - 196 + 1; gx = 0; }
        else              { gy = i - 292 + 1; gx = 97; }
        uint4* dst = (uint4*)(Xt + (((size_t)(b * 98 + gy)) * 98 + gx) * 256);
        uint4 zz; zz.x = zz.y = zz.z = zz.w = 0u;
        #pragma unroll
        for (int c = 0; c < 32; ++c) dst[c] = zz;
        return;
    }
    if (bid < 868) {
        int u = bid - 580;                 // 0..287
        int bx = u % 36;
        int rb = u / 36;                   // 0..7
        int b  = rb & 1;
        int cz = (rb >> 1) * 64;
        int px = bx * 256 + tid;           // 0..9215
        int gy = px / 96, gx = px - gy * 96;
        const float* src = x + (size_t)b * CINC_ * 9216;
        unsigned short* dst = Xt + (((size_t)(b * 98 + gy + 1)) * 98 + gx + 1) * 256;
        for (int c0 = cz; c0 < cz + 64; c0 += 8) {
            float f[8];
            #pragma unroll
            for (int t = 0; t < 8; ++t) f[t] = src[(size_t)(c0 + t) * 9216 + px];
            uint4 v;
            v.x = pk2(f[0], f[1]);
            v.y = pk2(f[2], f[3]);
            v.z = pk2(f[4], f[5]);
            v.w = pk2(f[6], f[7]);
            *(uint4*)&dst[c0] = v;
        }
        return;
    }
    // derived weights
    {
        int i = tid;
        if (i < 9) {
            int ci = i / 3, cj = i % 3;
            float a = 0.f;
            for (int c = 0; c < 64; ++c) a += w_q[c * 3 + ci] * w_q[c * 3 + cj];
            drv[i] = a;
        } else if (i < 12) {
            int ci = i - 9;
            float a = 0.f;
            for (int c = 0; c < 64; ++c) a += w_q[c * 3 + ci] * b_q[c];
            drv[i] = a;
        } else if (i == 12) {
            float a = 0.f;
            for (int c = 0; c < 64; ++c) a += b_q[c] * b_q[c];
            drv[12] = a;
        } else if (i < 70) {
            int idx = i - 13, ci = idx / 19, ov = idx % 19;
            float a = 0.f;
            for (int c = 0; c < 64; ++c) a += w_v[ov * 320 + 256 + c] * w_q[c * 3 + ci];
            drv[i] = a;
        } else if (i < 89) {
            int ov = i - 70;
            float a = b_v[ov];
            for (int c = 0; c < 64; ++c) a += w_v[ov * 320 + 256 + c] * b_q[c];
            drv[i] = a;
        }
        return;
    }
}

// ---------------- K_ec: MFMA conv3x3 (ec partial over 16 oc) + cv GEMM (z==0) --------
// grid (6, 12, 4*B): 16x8 px tile, oc-quarter z. 4 waves; wave wv: rows 2wv..2wv+1.
__global__ __launch_bounds__(256, 2) void k_ec(
    const unsigned short* __restrict__ Xt,
    const unsigned short* __restrict__ A_pk,
    const unsigned short* __restrict__ Avc,
    const float* __restrict__ b_ec, const float* __restrict__ w_eh,
    float* __restrict__ eh_part,         // (4,B,9216)
    float* __restrict__ cvb)             // (B,9216,20)
{
    __shared__ unsigned short sB[180 * 40];   // 10x18 halo px, 32ch chunk (80B stride)

    const int tid  = threadIdx.x;
    const int lane = tid & 63;
    const int wv   = tid >> 6;
    const int j    = lane & 15;
    const int g    = lane >> 4;
    const int zb   = blockIdx.z;
    const int z    = zb & 3;
    const int b    = zb >> 2;
    const int ty0  = blockIdx.y * 8;
    const int tx0  = blockIdx.x * 16;

    f32x4 acc[2];
    f32x4 accv[2][2];
    acc[0] = acc[1] = (f32x4)0.f;
    accv[0][0] = accv[0][1] = accv[1][0] = accv[1][1] = (f32x4)0.f;

    const bf16x8* Af  = (const bf16x8*)A_pk;
    const bf16x8* Avf = (const bf16x8*)Avc;

    for (int ck = 0; ck < 8; ++ck) {
        __syncthreads();
        for (int i = tid; i < 720; i += 256) {
            int px = i >> 2, part = i & 3;
            int ty = px / 18, tx = px - ty * 18;
            const unsigned short* src = Xt
                + (((size_t)(b * 98 + ty0 + ty)) * 98 + (tx0 + tx)) * 256
                + ck * 32 + part * 8;
            *(uint4*)&sB[px * 40 + part * 8] = *(const uint4*)src;
        }
        __syncthreads();

        #pragma unroll
        for (int tap = 0; tap < 9; ++tap) {
            const int dy = tap / 3, dx = tap % 3;
            bf16x8 b0 = *(const bf16x8*)&sB[((2 * wv + 0 + dy) * 18 + (j + dx)) * 40 + g * 8];
            bf16x8 b1 = *(const bf16x8*)&sB[((2 * wv + 1 + dy) * 18 + (j + dx)) * 40 + g * 8];
            bf16x8 a  = Af[((tap * 8 + ck) * 4 + z) * 64 + lane];
            acc[0] = __builtin_amdgcn_mfma_f32_16x16x32_bf16(a, b0, acc[0], 0, 0, 0);
            acc[1] = __builtin_amdgcn_mfma_f32_16x16x32_bf16(a, b1, acc[1], 0, 0, 0);
            if (z == 0 && tap == 4) {
                bf16x8 av0 = Avf[(ck * 2 + 0) * 64 + lane];
                bf16x8 av1 = Avf[(ck * 2 + 1) * 64 + lane];
                accv[0][0] = __builtin_amdgcn_mfma_f32_16x16x32_bf16(av0, b0, accv[0][0], 0, 0, 0);
                accv[0][1] = __builtin_amdgcn_mfma_f32_16x16x32_bf16(av0, b1, accv[0][1], 0, 0, 0);
                accv[1][0] = __builtin_amdgcn_mfma_f32_16x16x32_bf16(av1, b0, accv[1][0], 0, 0, 0);
                accv[1][1] = __builtin_amdgcn_mfma_f32_16x16x32_bf16(av1, b1, accv[1][1], 0, 0, 0);
            }
        }
    }

    float we[4], be[4];
    #pragma unroll
    for (int q = 0; q < 4; ++q) {
        int oc = z * 16 + 4 * g + q;
        we[q] = w_eh[oc];
        be[q] = b_ec[oc];
    }
    #pragma unroll
    for (int r = 0; r < 2; ++r) {
        float p = 0.f;
        #pragma unroll
        for (int q = 0; q < 4; ++q)
            p += we[q] * fmaxf(acc[r][q] + be[q], 0.f);
        p += __shfl_xor(p, 16);
        p += __shfl_xor(p, 32);
        const int gpix = (ty0 + 2 * wv + r) * WC_ + tx0 + j;
        if (g == 0)
            eh_part[((size_t)z * B_ + b) * (HC_ * WC_) + gpix] = p;
        if (z == 0) {
            float* cvp = cvb + ((size_t)b * (HC_ * WC_) + gpix) * 20;
            #pragma unroll
            for (int m = 0; m < 2; ++m)
                #pragma unroll
                for (int q = 0; q < 4; ++q) {
                    int ov = m * 16 + 4 * g + q;
                    if (ov < 20) cvp[ov] = accv[m][r][q];   // ov==19 writes 0 (Avc padded)
                }
        }
    }
}

// ---------------- K_fine: fused fine stage (linearized q, small-LDS) ----------------
// q (64-dim) is algebraically eliminated:
//   q_c.q_k = h . r_k + (u.r_c + s),  h = G r_c + u,  G = Wq^T Wq (3x3)
//   v = cv + bc + M r,                M = Wvq Wq (19x3), bc = b_v + Wvq b_q
__global__ __launch_bounds__(256, 4) void k_fine(
    const float* __restrict__ raw,
    const float* __restrict__ w_ef, const float* __restrict__ b_ef,
    const float* __restrict__ w_eh,
    const float* __restrict__ drv,           // 89 derived floats
    const float* __restrict__ eh_g,          // (4,B,9216)
    const float* __restrict__ cvb,           // (B,9216,20)
    float* __restrict__ out_y,
    float* __restrict__ out_ne)
{
    __shared__ float sRaw[3][20][20];          // 4.8 KB
    __shared__ unsigned short sV[324 * 26];    // 16.8 KB: words 0..9 = v[0..18] bf16 pairs
    __shared__ float sNE[324];                 // 1.3 KB

    const int tid = threadIdx.x;
    const int b   = blockIdx.z;
    const int ty0 = blockIdx.y * 16;
    const int tx0 = blockIdx.x * 16;
    const float* rb = raw + (size_t)b * 3 * (HF_ * WF_);

    const float* Gm = drv;          // 9
    const float* uv = drv + 9;      // 3
    const float* Mm = drv + 13;     // [ci*19+ov]
    const float* bc = drv + 70;     // 19

    // Phase 0: stage raw 20x20x3 (zero-padded, 2-px halo)
    for (int i = tid; i < 1200; i += 256) {
        int ch = i / 400, rem = i - ch * 400;
        int ry = rem / 20, rx = rem - ry * 20;
        int gh = ty0 + ry - 2, gw = tx0 + rx - 2;
        float v = 0.f;
        if (gh >= 0 && gh < HF_ && gw >= 0 && gw < WF_)
            v = rb[(size_t)ch * (HF_ * WF_) + gh * WF_ + gw];
        sRaw[ch][ry][rx] = v;
    }
    __syncthreads();

    // Phase A: per halo pixel (18x18): ef -> ne ; v = bc + cv + M.r -> sV
    for (int p = tid; p < 324; p += 256) {
        const int iy = p / 18, ix = p - iy * 18;
        const int gh = ty0 + iy - 1, gw = tx0 + ix - 1;
        unsigned int* vw = (unsigned int*)&sV[p * 26];
        if (gh < 0 || gh >= HF_ || gw < 0 || gw >= WF_) {
            #pragma unroll
            for (int w = 0; w < 10; ++w) vw[w] = 0u;
            sNE[p] = 0.f;
            continue;
        }
        float ef = b_ef[0];
        #pragma unroll
        for (int ci = 0; ci < 3; ++ci)
            #pragma unroll
            for (int t = 0; t < 9; ++t)
                ef = fmaf(w_ef[ci * 9 + t], sRaw[ci][iy + t / 3][ix + t % 3], ef);
        ef = fmaxf(ef, 0.f);

        const int cpix = (gh >> 2) * WC_ + (gw >> 2);
        float logit = w_eh[64] * ef;
        #pragma unroll
        for (int zz = 0; zz < 4; ++zz)
            logit += eh_g[((size_t)zz * B_ + b) * (HC_ * WC_) + cpix];
        float ne = 1.f / (1.f + __expf(-logit));
        sNE[p] = ne;

        const float r0 = sRaw[0][iy + 1][ix + 1];
        const float r1 = sRaw[1][iy + 1][ix + 1];
        const float r2 = sRaw[2][iy + 1][ix + 1];

        float v[20];
        {
            const float4* cvp = (const float4*)(cvb + ((size_t)b * (HC_ * WC_) + cpix) * 20);
            float4 c0 = cvp[0], c1 = cvp[1], c2 = cvp[2], c3 = cvp[3], c4 = cvp[4];
            v[0] = c0.x; v[1] = c0.y; v[2] = c0.z; v[3] = c0.w;
            v[4] = c1.x; v[5] = c1.y; v[6] = c1.z; v[7] = c1.w;
            v[8] = c2.x; v[9] = c2.y; v[10] = c2.z; v[11] = c2.w;
            v[12] = c3.x; v[13] = c3.y; v[14] = c3.z; v[15] = c3.w;
            v[16] = c4.x; v[17] = c4.y; v[18] = c4.z;
        }
        #pragma unroll
        for (int ov = 0; ov < COUT_; ++ov)
            v[ov] = fmaf(Mm[38 + ov], r2,
                    fmaf(Mm[19 + ov], r1,
                    fmaf(Mm[ov], r0, v[ov] + bc[ov])));

        #pragma unroll
        for (int o2 = 0; o2 < 9; ++o2)
            vw[o2] = pk2(v[2 * o2], v[2 * o2 + 1]);
        vw[9] = (unsigned int)f2bf(v[18]);
    }
    __syncthreads();

    // Phase B: per own pixel — 3-dim score algebra, softmax, PV
    const int py = tid >> 4, px2 = tid & 15;
    const int iy = py + 1, ix = px2 + 1;
    const int pbase = iy * 18 + ix;

    float rn[3][9];
    #pragma unroll
    for (int ci = 0; ci < 3; ++ci)
        #pragma unroll
        for (int k = 0; k < 9; ++k)
            rn[ci][k] = sRaw[ci][iy + k / 3][ix + k % 3];

    const float rc0 = rn[0][4], rc1 = rn[1][4], rc2 = rn[2][4];
    // h = G r_c + u ; ac = u.r_c + s
    const float h0 = fmaf(Gm[0], rc0, fmaf(Gm[1], rc1, fmaf(Gm[2], rc2, uv[0])));
    const float h1 = fmaf(Gm[3], rc0, fmaf(Gm[4], rc1, fmaf(Gm[5], rc2, uv[1])));
    const float h2 = fmaf(Gm[6], rc0, fmaf(Gm[7], rc1, fmaf(Gm[8], rc2, uv[2])));
    const float ac = fmaf(uv[0], rc0, fmaf(uv[1], rc1, fmaf(uv[2], rc2, drv[12])));

    float sc[9];
    #pragma unroll
    for (int k = 0; k < 9; ++k) {
        float d = fmaf(h0, rn[0][k], fmaf(h1, rn[1][k], fmaf(h2, rn[2][k], ac)));
        const int pn = pbase + (k / 3 - 1) * 18 + (k % 3 - 1);
        sc[k] = sNE[pn] * d;
    }
    float mmax = sc[0];
    #pragma unroll
    for (int k = 1; k < 9; ++k) mmax = fmaxf(mmax, sc[k]);
    float e[9];
    float ssum = 0.f;
    #pragma unroll
    for (int k = 0; k < 9; ++k) { e[k] = __expf(sc[k] - mmax); ssum += e[k]; }
    const float inv = 1.f / ssum;

    float y[COUT_];
    #pragma unroll
    for (int ov = 0; ov < COUT_; ++ov) y[ov] = 0.f;
    #pragma unroll
    for (int k = 0; k < 9; ++k) {
        const int pn = pbase + (k / 3 - 1) * 18 + (k % 3 - 1);
        const float a = e[k] * inv;
        const unsigned int* vp = (const unsigned int*)&sV[pn * 26];
        #pragma unroll
        for (int o2 = 0; o2 < 9; ++o2) {
            unsigned int u = vp[o2];
            y[2 * o2]     = fmaf(a, bflo(u), y[2 * o2]);
            y[2 * o2 + 1] = fmaf(a, bfhi(u), y[2 * o2 + 1]);
        }
        y[18] = fmaf(a, bflo(vp[9]), y[18]);
    }

    const int gh = ty0 + py, gw = tx0 + px2;
    const size_t ppos = (size_t)gh * WF_ + gw;
    #pragma unroll
    for (int ov = 0; ov < COUT_; ++ov)
        out_y[((size_t)b * COUT_ + ov) * (HF_ * WF_) + ppos] = y[ov];
    out_ne[(size_t)b * (HF_ * WF_) + ppos] = sNE[pbase];
}

// ---------------- launch ----------------
extern "C" void kernel_launch(void* const* d_in, const int* in_sizes, int n_in,
                              void* d_out, int out_size, void* d_ws, size_t ws_size,
                              hipStream_t stream)
{
    const float* coarse = (const float*)d_in[0];
    const float* raw    = (const float*)d_in[1];
    const float* w_ef   = (const float*)d_in[2];
    const float* b_ef   = (const float*)d_in[3];
    const float* w_ec   = (const float*)d_in[4];
    const float* b_ec   = (const float*)d_in[5];
    const float* w_eh   = (const float*)d_in[6];
    const float* w_q    = (const float*)d_in[7];
    const float* b_q    = (const float*)d_in[8];
    const float* w_v    = (const float*)d_in[9];
    const float* b_v    = (const float*)d_in[10];
    (void)in_sizes; (void)n_in; (void)out_size; (void)ws_size;

    unsigned char* ws = (unsigned char*)d_ws;
    size_t off = 0;
    unsigned short* Xt    = (unsigned short*)(ws + off); off += (size_t)B_ * 98 * 98 * 256 * 2; // 9,834,496
    unsigned short* A_pk  = (unsigned short*)(ws + off); off += 294912;
    unsigned short* Avc   = (unsigned short*)(ws + off); off += 16384;
    float* eh     = (float*)(ws + off); off += (size_t)4 * B_ * 9216 * 4;   // 294,912
    float* cvb    = (float*)(ws + off); off += (size_t)B_ * 9216 * 20 * 4;  // 1,474,560
    float* drv    = (float*)(ws + off); off += 512;

    float* out_y  = (float*)d_out;
    float* out_ne = out_y + (size_t)B_ * COUT_ * HF_ * WF_;

    hipLaunchKernelGGL(k_pre, dim3(869), dim3(256), 0, stream,
                       coarse, w_ec, w_v, w_q, b_q, b_v, Xt, A_pk, Avc, drv);
    hipLaunchKernelGGL(k_ec, dim3(6, 12, 4 * B_), dim3(256), 0, stream,
                       Xt, A_pk, Avc, b_ec, w_eh, eh, cvb);
    hipLaunchKernelGGL(k_fine, dim3(24, 24, B_), dim3(256), 0, stream,
                       raw, w_ef, b_ef, w_eh, drv, eh, cvb, out_y, out_ne);
}

// Round 8
// 53.422 us; speedup vs baseline: 5.6395x; 1.1816x over previous
//
#include <hip/hip_runtime.h>
#include <math.h>

#define B_    2
#define HC_   96
#define WC_   96
#define HF_   384
#define WF_   384
#define CINC_ 256
#define CH_   64
#define COUT_ 19

typedef __attribute__((ext_vector_type(8))) short bf16x8;
typedef __attribute__((ext_vector_type(4))) float f32x4;

__device__ __forceinline__ unsigned short f2bf(float f) {
    unsigned int u = __float_as_uint(f);
    u += 0x7fffu + ((u >> 16) & 1u);
    return (unsigned short)(u >> 16);
}
__device__ __forceinline__ unsigned int pk2(float a, float b) {
    return (unsigned int)f2bf(a) | ((unsigned int)f2bf(b) << 16);
}
__device__ __forceinline__ float bflo(unsigned int u) { return __uint_as_float(u << 16); }
__device__ __forceinline__ float bfhi(unsigned int u) { return __uint_as_float(u & 0xffff0000u); }

__device__ __forceinline__ void gl_lds16(const void* g, void* l) {
    __builtin_amdgcn_global_load_lds(
        (const __attribute__((address_space(1))) void*)g,
        (__attribute__((address_space(3))) void*)l, 16, 0, 0);
}

// ---------------- K_pre: merged prep + border-zero + transpose + derived weights ----
// bid <576    : weight prep (A_pk, Avc)
// bid 576-579 : zero 1-px border of Xt
// bid 580-1155: coarse (B,256,96,96) f32 -> Xt (B,98,98,256) bf16 (interior, 32-ch chunks)
// bid 1156    : derived weights drv[89]
__global__ __launch_bounds__(256) void k_pre(
    const float* __restrict__ x,      // coarse
    const float* __restrict__ w_ec, const float* __restrict__ w_v,
    const float* __restrict__ w_q,  const float* __restrict__ b_q,
    const float* __restrict__ b_v,
    unsigned short* __restrict__ Xt,
    unsigned short* __restrict__ A_pk, unsigned short* __restrict__ Avc,
    float* __restrict__ drv)
{
    const int bid = blockIdx.x;
    const int tid = threadIdx.x;
    if (bid < 576) {
        int i = bid * 256 + tid;
        // A_pk (9,8,4,64,8): ec weights in 16x16x32 A-frag layout
        {
            int e = i & 7, l = (i >> 3) & 63, m = (i >> 9) & 3, ck = (i >> 11) & 7, tap = i >> 14;
            int oc = m * 16 + (l & 15);
            int ch = ck * 32 + (l >> 4) * 8 + e;
            A_pk[i] = f2bf(w_ec[(oc * 256 + ch) * 9 + tap]);
        }
        if (i < 8192) {  // Avc (8,2,64,8): w_v[:, :256], ov>=19 -> 0
            int e = i & 7, l = (i >> 3) & 63, m = (i >> 9) & 1, ck = (i >> 10) & 7;
            int ov = m * 16 + (l & 15);
            int ch = ck * 32 + (l >> 4) * 8 + e;
            Avc[i] = (ov < COUT_) ? f2bf(w_v[ov * 320 + ch]) : (unsigned short)0;
        }
        return;
    }
    if (bid < 580) {
        int e = (bid - 576) * 256 + tid;
        if (e >= 388 * B_) return;
        int b = e / 388, i = e - b * 388;
        int gy, gx;
        if (i < 98)       { gy = 0;           gx = i; }
        else if (i < 196) { gy = 97;          gx = i - 98; }
        else if (i < 292) { gy = i - 196 + 1; gx = 0; }
        else              { gy = i - 292 + 1; gx = 97; }
        uint4* dst = (uint4*)(Xt + (((size_t)(b * 98 + gy)) * 98 + gx) * 256);
        uint4 zz; zz.x = zz.y = zz.z = zz.w = 0u;
        #pragma unroll
        for (int c = 0; c < 32; ++c) dst[c] = zz;
        return;
    }
    if (bid < 1156) {
        int u = bid - 580;                 // 0..575
        int bx = u % 36;
        int rb = u / 36;                   // 0..15
        int b  = rb & 1;
        int cz = (rb >> 1) * 32;
        int px = bx * 256 + tid;           // 0..9215
        int gy = px / 96, gx = px - gy * 96;
        const float* src = x + (size_t)b * CINC_ * 9216;
        unsigned short* dst = Xt + (((size_t)(b * 98 + gy + 1)) * 98 + gx + 1) * 256;
        for (int c0 = cz; c0 < cz + 32; c0 += 8) {
            float f[8];
            #pragma unroll
            for (int t = 0; t < 8; ++t) f[t] = src[(size_t)(c0 + t) * 9216 + px];
            uint4 v;
            v.x = pk2(f[0], f[1]);
            v.y = pk2(f[2], f[3]);
            v.z = pk2(f[4], f[5]);
            v.w = pk2(f[6], f[7]);
            *(uint4*)&dst[c0] = v;
        }
        return;
    }
    // derived weights
    {
        int i = tid;
        if (i < 9) {
            int ci = i / 3, cj = i % 3;
            float a = 0.f;
            for (int c = 0; c < 64; ++c) a += w_q[c * 3 + ci] * w_q[c * 3 + cj];
            drv[i] = a;
        } else if (i < 12) {
            int ci = i - 9;
            float a = 0.f;
            for (int c = 0; c < 64; ++c) a += w_q[c * 3 + ci] * b_q[c];
            drv[i] = a;
        } else if (i == 12) {
            float a = 0.f;
            for (int c = 0; c < 64; ++c) a += b_q[c] * b_q[c];
            drv[12] = a;
        } else if (i < 70) {
            int idx = i - 13, ci = idx / 19, ov = idx % 19;
            float a = 0.f;
            for (int c = 0; c < 64; ++c) a += w_v[ov * 320 + 256 + c] * w_q[c * 3 + ci];
            drv[i] = a;
        } else if (i < 89) {
            int ov = i - 70;
            float a = b_v[ov];
            for (int c = 0; c < 64; ++c) a += w_v[ov * 320 + 256 + c] * b_q[c];
            drv[i] = a;
        }
        return;
    }
}

// ---------------- K_ec: MFMA conv3x3 (16 oc quarter) + cv GEMM (z==0) ---------------
// grid (6,12,4*B). 16x8 px tile, 4 waves (2-row strips). Async dbuf staging via
// global_load_lds into linear LDS slots with XOR pre-swizzle (T21): slot content
// part = (slot&3) ^ ((px>>1)&3); read applies the same XOR -> 2-way banks (free).
__global__ __launch_bounds__(256, 2) void k_ec(
    const unsigned short* __restrict__ Xt,
    const unsigned short* __restrict__ A_pk,
    const unsigned short* __restrict__ Avc,
    const float* __restrict__ b_ec, const float* __restrict__ w_eh,
    float* __restrict__ eh4,             // (B,9216,4)
    float* __restrict__ cvb)             // (B,9216,20)
{
    __shared__ uint4 sB[2][768];   // 2 x 12 KB; slots [px*4 + swz(part)]

    const int tid  = threadIdx.x;
    const int lane = tid & 63;
    const int wv   = tid >> 6;
    const int j    = lane & 15;
    const int g    = lane >> 4;
    const int zb   = blockIdx.z;
    const int z    = zb & 3;
    const int b    = zb >> 2;
    const int ty0  = blockIdx.y * 8;
    const int tx0  = blockIdx.x * 16;

    f32x4 acc0 = (f32x4)0.f, acc1 = (f32x4)0.f;
    f32x4 accv[2][2];
    accv[0][0] = accv[0][1] = accv[1][0] = accv[1][1] = (f32x4)0.f;

    const bf16x8* Af  = (const bf16x8*)A_pk;
    const bf16x8* Avf = (const bf16x8*)Avc;

#define STAGE_EC(BUF, CK)                                                      \
    {                                                                          \
        _Pragma("unroll")                                                      \
        for (int rr = 0; rr < 3; ++rr) {                                       \
            int slot = 192 * wv + 64 * rr + lane;                              \
            int px = slot >> 2;                                                \
            px = px > 179 ? 179 : px;                                          \
            int part = (slot & 3) ^ ((px >> 1) & 3);                           \
            int row = px / 18, col = px - row * 18;                            \
            const unsigned short* src = Xt                                     \
                + (((size_t)(b * 98 + ty0 + row)) * 98 + (tx0 + col)) * 256    \
                + (CK) * 32 + part * 8;                                        \
            gl_lds16(src, &sB[BUF][192 * wv + 64 * rr]);                       \
        }                                                                      \
    }

    STAGE_EC(0, 0);
    __syncthreads();   // drains vmcnt

    for (int ck = 0; ck < 8; ++ck) {
        const int cur = ck & 1;
        if (ck < 7) STAGE_EC(cur ^ 1, ck + 1);

        // register-cache the 12 unique B-frags (4 rows x 3 cols)
        bf16x8 frg[4][3];
        #pragma unroll
        for (int rr = 0; rr < 4; ++rr)
            #pragma unroll
            for (int dx = 0; dx < 3; ++dx) {
                int px = (2 * wv + rr) * 18 + j + dx;
                int slot = (px << 2) + (g ^ ((px >> 1) & 3));
                frg[rr][dx] = *(const bf16x8*)&sB[cur][slot];
            }

        #pragma unroll
        for (int tap = 0; tap < 9; ++tap) {
            const int dy = tap / 3, dx = tap % 3;
            bf16x8 a = Af[((tap * 8 + ck) * 4 + z) * 64 + lane];
            acc0 = __builtin_amdgcn_mfma_f32_16x16x32_bf16(a, frg[dy][dx], acc0, 0, 0, 0);
            acc1 = __builtin_amdgcn_mfma_f32_16x16x32_bf16(a, frg[dy + 1][dx], acc1, 0, 0, 0);
        }
        if (z == 0) {  // cv GEMM on the center tap's B-frags
            bf16x8 av0 = Avf[(ck * 2 + 0) * 64 + lane];
            bf16x8 av1 = Avf[(ck * 2 + 1) * 64 + lane];
            accv[0][0] = __builtin_amdgcn_mfma_f32_16x16x32_bf16(av0, frg[1][1], accv[0][0], 0, 0, 0);
            accv[0][1] = __builtin_amdgcn_mfma_f32_16x16x32_bf16(av0, frg[2][1], accv[0][1], 0, 0, 0);
            accv[1][0] = __builtin_amdgcn_mfma_f32_16x16x32_bf16(av1, frg[1][1], accv[1][0], 0, 0, 0);
            accv[1][1] = __builtin_amdgcn_mfma_f32_16x16x32_bf16(av1, frg[2][1], accv[1][1], 0, 0, 0);
        }
        if (ck < 7) __syncthreads();
    }
#undef STAGE_EC

    float we[4], be[4];
    #pragma unroll
    for (int q = 0; q < 4; ++q) {
        int oc = z * 16 + 4 * g + q;
        we[q] = w_eh[oc];
        be[q] = b_ec[oc];
    }
    #pragma unroll
    for (int r = 0; r < 2; ++r) {
        const f32x4 accr = r ? acc1 : acc0;
        float p = 0.f;
        #pragma unroll
        for (int q = 0; q < 4; ++q)
            p += we[q] * fmaxf(accr[q] + be[q], 0.f);
        p += __shfl_xor(p, 16);
        p += __shfl_xor(p, 32);
        const int gpix = (ty0 + 2 * wv + r) * WC_ + tx0 + j;
        if (g == 0)
            eh4[((size_t)b * (HC_ * WC_) + gpix) * 4 + z] = p;
        if (z == 0) {
            float* cvp = cvb + ((size_t)b * (HC_ * WC_) + gpix) * 20;
            #pragma unroll
            for (int m = 0; m < 2; ++m)
                #pragma unroll
                for (int q = 0; q < 4; ++q) {
                    int ov = m * 16 + 4 * g + q;
                    if (ov < 20) cvp[ov] = accv[m][r][q];   // ov==19 writes 0 (Avc padded)
                }
        }
    }
}

// ---------------- K_fine: fused fine stage (linearized q, small-LDS) ----------------
__global__ __launch_bounds__(256, 4) void k_fine(
    const float* __restrict__ raw,
    const float* __restrict__ w_ef, const float* __restrict__ b_ef,
    const float* __restrict__ w_eh,
    const float* __restrict__ drv,           // 89 derived floats
    const float* __restrict__ eh4,           // (B,9216,4)
    const float* __restrict__ cvb,           // (B,9216,20)
    float* __restrict__ out_y,
    float* __restrict__ out_ne)
{
    __shared__ float sRaw[3][20][20];          // 4.8 KB
    __shared__ unsigned short sV[324 * 26];    // 16.8 KB
    __shared__ float sNE[324];                 // 1.3 KB

    const int tid = threadIdx.x;
    const int b   = blockIdx.z;
    const int ty0 = blockIdx.y * 16;
    const int tx0 = blockIdx.x * 16;
    const float* rb = raw + (size_t)b * 3 * (HF_ * WF_);

    const float* Gm = drv;          // 9
    const float* uv = drv + 9;      // 3
    const float* Mm = drv + 13;     // [ci*19+ov]
    const float* bc = drv + 70;     // 19

    // Phase 0: stage raw 20x20x3 (zero-padded, 2-px halo)
    for (int i = tid; i < 1200; i += 256) {
        int ch = i / 400, rem = i - ch * 400;
        int ry = rem / 20, rx = rem - ry * 20;
        int gh = ty0 + ry - 2, gw = tx0 + rx - 2;
        float v = 0.f;
        if (gh >= 0 && gh < HF_ && gw >= 0 && gw < WF_)
            v = rb[(size_t)ch * (HF_ * WF_) + gh * WF_ + gw];
        sRaw[ch][ry][rx] = v;
    }
    __syncthreads();

    // Phase A: per halo pixel (18x18): ef -> ne ; v = bc + cv + M.r -> sV
    for (int p = tid; p < 324; p += 256) {
        const int iy = p / 18, ix = p - iy * 18;
        const int gh = ty0 + iy - 1, gw = tx0 + ix - 1;
        unsigned int* vw = (unsigned int*)&sV[p * 26];
        if (gh < 0 || gh >= HF_ || gw < 0 || gw >= WF_) {
            #pragma unroll
            for (int w = 0; w < 10; ++w) vw[w] = 0u;
            sNE[p] = 0.f;
            continue;
        }
        float ef = b_ef[0];
        #pragma unroll
        for (int ci = 0; ci < 3; ++ci)
            #pragma unroll
            for (int t = 0; t < 9; ++t)
                ef = fmaf(w_ef[ci * 9 + t], sRaw[ci][iy + t / 3][ix + t % 3], ef);
        ef = fmaxf(ef, 0.f);

        const int cpix = (gh >> 2) * WC_ + (gw >> 2);
        const float4 ehv = *(const float4*)(eh4 + ((size_t)b * (HC_ * WC_) + cpix) * 4);
        float logit = fmaf(w_eh[64], ef, (ehv.x + ehv.y) + (ehv.z + ehv.w));
        float ne = 1.f / (1.f + __expf(-logit));
        sNE[p] = ne;

        const float r0 = sRaw[0][iy + 1][ix + 1];
        const float r1 = sRaw[1][iy + 1][ix + 1];
        const float r2 = sRaw[2][iy + 1][ix + 1];

        float v[20];
        {
            const float4* cvp = (const float4*)(cvb + ((size_t)b * (HC_ * WC_) + cpix) * 20);
            float4 c0 = cvp[0], c1 = cvp[1], c2 = cvp[2], c3 = cvp[3], c4 = cvp[4];
            v[0] = c0.x; v[1] = c0.y; v[2] = c0.z; v[3] = c0.w;
            v[4] = c1.x; v[5] = c1.y; v[6] = c1.z; v[7] = c1.w;
            v[8] = c2.x; v[9] = c2.y; v[10] = c2.z; v[11] = c2.w;
            v[12] = c3.x; v[13] = c3.y; v[14] = c3.z; v[15] = c3.w;
            v[16] = c4.x; v[17] = c4.y; v[18] = c4.z;
        }
        #pragma unroll
        for (int ov = 0; ov < COUT_; ++ov)
            v[ov] = fmaf(Mm[38 + ov], r2,
                    fmaf(Mm[19 + ov], r1,
                    fmaf(Mm[ov], r0, v[ov] + bc[ov])));

        #pragma unroll
        for (int o2 = 0; o2 < 9; ++o2)
            vw[o2] = pk2(v[2 * o2], v[2 * o2 + 1]);
        vw[9] = (unsigned int)f2bf(v[18]);
    }
    __syncthreads();

    // Phase B: per own pixel — 3-dim score algebra, softmax, PV
    const int py = tid >> 4, px2 = tid & 15;
    const int iy = py + 1, ix = px2 + 1;
    const int pbase = iy * 18 + ix;

    float rn[3][9];
    #pragma unroll
    for (int ci = 0; ci < 3; ++ci)
        #pragma unroll
        for (int k = 0; k < 9; ++k)
            rn[ci][k] = sRaw[ci][iy + k / 3][ix + k % 3];

    const float rc0 = rn[0][4], rc1 = rn[1][4], rc2 = rn[2][4];
    const float h0 = fmaf(Gm[0], rc0, fmaf(Gm[1], rc1, fmaf(Gm[2], rc2, uv[0])));
    const float h1 = fmaf(Gm[3], rc0, fmaf(Gm[4], rc1, fmaf(Gm[5], rc2, uv[1])));
    const float h2 = fmaf(Gm[6], rc0, fmaf(Gm[7], rc1, fmaf(Gm[8], rc2, uv[2])));
    const float ac = fmaf(uv[0], rc0, fmaf(uv[1], rc1, fmaf(uv[2], rc2, drv[12])));

    float sc[9];
    #pragma unroll
    for (int k = 0; k < 9; ++k) {
        float d = fmaf(h0, rn[0][k], fmaf(h1, rn[1][k], fmaf(h2, rn[2][k], ac)));
        const int pn = pbase + (k / 3 - 1) * 18 + (k % 3 - 1);
        sc[k] = sNE[pn] * d;
    }
    float mmax = sc[0];
    #pragma unroll
    for (int k = 1; k < 9; ++k) mmax = fmaxf(mmax, sc[k]);
    float e[9];
    float ssum = 0.f;
    #pragma unroll
    for (int k = 0; k < 9; ++k) { e[k] = __expf(sc[k] - mmax); ssum += e[k]; }
    const float inv = 1.f / ssum;

    float y[COUT_];
    #pragma unroll
    for (int ov = 0; ov < COUT_; ++ov) y[ov] = 0.f;
    #pragma unroll
    for (int k = 0; k < 9; ++k) {
        const int pn = pbase + (k / 3 - 1) * 18 + (k % 3 - 1);
        const float a = e[k] * inv;
        const unsigned int* vp = (const unsigned int*)&sV[pn * 26];
        #pragma unroll
        for (int o2 = 0; o2 < 9; ++o2) {
            unsigned int u = vp[o2];
            y[2 * o2]     = fmaf(a, bflo(u), y[2 * o2]);
            y[2 * o2 + 1] = fmaf(a, bfhi(u), y[2 * o2 + 1]);
        }
        y[18] = fmaf(a, bflo(vp[9]), y[18]);
    }

    const int gh = ty0 + py, gw = tx0 + px2;
    const size_t ppos = (size_t)gh * WF_ + gw;
    #pragma unroll
    for (int ov = 0; ov < COUT_; ++ov)
        out_y[((size_t)b * COUT_ + ov) * (HF_ * WF_) + ppos] = y[ov];
    out_ne[(size_t)b * (HF_ * WF_) + ppos] = sNE[pbase];
}

// ---------------- launch ----------------
extern "C" void kernel_launch(void* const* d_in, const int* in_sizes, int n_in,
                              void* d_out, int out_size, void* d_ws, size_t ws_size,
                              hipStream_t stream)
{
    const float* coarse = (const float*)d_in[0];
    const float* raw    = (const float*)d_in[1];
    const float* w_ef   = (const float*)d_in[2];
    const float* b_ef   = (const float*)d_in[3];
    const float* w_ec   = (const float*)d_in[4];
    const float* b_ec   = (const float*)d_in[5];
    const float* w_eh   = (const float*)d_in[6];
    const float* w_q    = (const float*)d_in[7];
    const float* b_q    = (const float*)d_in[8];
    const float* w_v    = (const float*)d_in[9];
    const float* b_v    = (const float*)d_in[10];
    (void)in_sizes; (void)n_in; (void)out_size; (void)ws_size;

    unsigned char* ws = (unsigned char*)d_ws;
    size_t off = 0;
    unsigned short* Xt    = (unsigned short*)(ws + off); off += (size_t)B_ * 98 * 98 * 256 * 2; // 9,834,496
    unsigned short* A_pk  = (unsigned short*)(ws + off); off += 294912;
    unsigned short* Avc   = (unsigned short*)(ws + off); off += 16384;
    float* eh4    = (float*)(ws + off); off += (size_t)B_ * 9216 * 4 * 4;   // 294,912
    float* cvb    = (float*)(ws + off); off += (size_t)B_ * 9216 * 20 * 4;  // 1,474,560
    float* drv    = (float*)(ws + off); off += 512;

    float* out_y  = (float*)d_out;
    float* out_ne = out_y + (size_t)B_ * COUT_ * HF_ * WF_;

    hipLaunchKernelGGL(k_pre, dim3(1157), dim3(256), 0, stream,
                       coarse, w_ec, w_v, w_q, b_q, b_v, Xt, A_pk, Avc, drv);
    hipLaunchKernelGGL(k_ec, dim3(6, 12, 4 * B_), dim3(256), 0, stream,
                       Xt, A_pk, Avc, b_ec, w_eh, eh4, cvb);
    hipLaunchKernelGGL(k_fine, dim3(24, 24, B_), dim3(256), 0, stream,
                       raw, w_ef, b_ef, w_eh, drv, eh4, cvb, out_y, out_ne);
}